// Round 3
// baseline (4667.459 us; speedup 1.0000x reference)
//
#include <hip/hip_runtime.h>
#include <hip/hip_bf16.h>
#include <stdint.h>

// SimpleRNN: B=64, S=512, H=1024, V=128
// Phase 0: pack W_out -> bf16 MFMA-B-fragment layout in device global
// Phase 1: persistent 16-wg recurrence, W_hh slice resident in LDS (bf16),
//          h exchanged via AGENT-scope (sc1) loads/stores -> no L2 flush/inv
// Phase 2: logits GEMM (hidden bf16 @ W_out bf16, fp32 accum) + b_out

#define Bz 64
#define Sz 512
#define Hz 1024
#define Vz 128
#define NWG 16
#define COLS 64   // Hz / NWG columns of W_hh per workgroup
#define WGT 512   // threads per wg (8 waves): 2 M-tiles x 4 K-splits

typedef __attribute__((ext_vector_type(8)))  short short8;
typedef __attribute__((ext_vector_type(16))) float f32x16;
typedef __attribute__((ext_vector_type(4)))  float f32x4;

// device-global scratch (.bss, rewritten every call)
// g_hbuf typed as u64 so agent-scope 8B atomics are provably aligned.
__device__ __align__(16) unsigned long long g_hbuf[2][(Bz * Hz) / 4];
__device__ __align__(16) unsigned short g_hidden[(size_t)Bz*Sz*Hz]; // 64 MB hidden states
__device__ __align__(16) unsigned short g_wout[Hz*Vz];              // packed W_out [kb][v][8]

__device__ __forceinline__ unsigned short f2bf(float f) {
  union { float f; unsigned u; } v; v.f = f;
  unsigned r = v.u + 0x7FFFu + ((v.u >> 16) & 1u);      // RNE
  return (unsigned short)(r >> 16);
}

__device__ __forceinline__ float fast_tanh(float x) {
  float cx = fminf(9.0f, fmaxf(-9.0f, x));
  float e  = __builtin_amdgcn_exp2f(cx * 2.88539008178f);   // e^(2x)
  return (e - 1.0f) * __builtin_amdgcn_rcpf(e + 1.0f);
}

// 16x coherent (device-scope, sc1: bypass vL1+L2, served at L3) 16B loads of one
// thread's contiguous 512B A-fragment region; single internal vmcnt drain.
__device__ __forceinline__ void load_afrags(const unsigned short* p, uint4 t[16]) {
  asm volatile(
    "global_load_dwordx4 %0,  %16, off sc1\n\t"
    "global_load_dwordx4 %1,  %16, off offset:32 sc1\n\t"
    "global_load_dwordx4 %2,  %16, off offset:64 sc1\n\t"
    "global_load_dwordx4 %3,  %16, off offset:96 sc1\n\t"
    "global_load_dwordx4 %4,  %16, off offset:128 sc1\n\t"
    "global_load_dwordx4 %5,  %16, off offset:160 sc1\n\t"
    "global_load_dwordx4 %6,  %16, off offset:192 sc1\n\t"
    "global_load_dwordx4 %7,  %16, off offset:224 sc1\n\t"
    "global_load_dwordx4 %8,  %16, off offset:256 sc1\n\t"
    "global_load_dwordx4 %9,  %16, off offset:288 sc1\n\t"
    "global_load_dwordx4 %10, %16, off offset:320 sc1\n\t"
    "global_load_dwordx4 %11, %16, off offset:352 sc1\n\t"
    "global_load_dwordx4 %12, %16, off offset:384 sc1\n\t"
    "global_load_dwordx4 %13, %16, off offset:416 sc1\n\t"
    "global_load_dwordx4 %14, %16, off offset:448 sc1\n\t"
    "global_load_dwordx4 %15, %16, off offset:480 sc1\n\t"
    "s_waitcnt vmcnt(0)"
    : "=&v"(t[0]), "=&v"(t[1]), "=&v"(t[2]),  "=&v"(t[3]),
      "=&v"(t[4]), "=&v"(t[5]), "=&v"(t[6]),  "=&v"(t[7]),
      "=&v"(t[8]), "=&v"(t[9]), "=&v"(t[10]), "=&v"(t[11]),
      "=&v"(t[12]),"=&v"(t[13]),"=&v"(t[14]), "=&v"(t[15])
    : "v"(p)
    : "memory");
}

// ---------------- Phase 0: pack W_out (H,V) fp32 -> [kb][v][8] bf16 ----------
__global__ void pack_wout(const float* __restrict__ W_out) {
  int gid = blockIdx.x * blockDim.x + threadIdx.x;      // 0..16383 (kb*128+v)
  int v  = gid & (Vz - 1);
  int kb = gid >> 7;
  unsigned short t[8];
#pragma unroll
  for (int j = 0; j < 8; ++j)
    t[j] = f2bf(W_out[(size_t)(kb * 8 + j) * Vz + v]);
  uint4 w;
  w.x = (unsigned)t[0] | ((unsigned)t[1] << 16);
  w.y = (unsigned)t[2] | ((unsigned)t[3] << 16);
  w.z = (unsigned)t[4] | ((unsigned)t[5] << 16);
  w.w = (unsigned)t[6] | ((unsigned)t[7] << 16);
  *(uint4*)&g_wout[(size_t)gid * 8] = w;
}

// ---------------- Phase 1: persistent recurrence -----------------------------
__global__ __launch_bounds__(WGT) void rnn_persistent(
    const int* __restrict__ x, const float* __restrict__ h0,
    const float* __restrict__ W_xh, const float* __restrict__ W_hh,
    const float* __restrict__ b_h, float* __restrict__ out,
    unsigned* __restrict__ ctr)
{
  // W slice, fragment layout [kb=k/8][n][j] -> conflict-minimal ds_read_b128
  __shared__ unsigned short ldsW[128 * COLS * 8];       // 128 KB
  __shared__ float red[2][32][COLS];                    // 16 KB K-split reduction

  const int g    = blockIdx.x;        // 0..15
  const int n0g  = g * COLS;          // global column base of this wg's W slice
  const int tid  = threadIdx.x;
  const int lane = tid & 63;
  const int wv   = tid >> 6;          // 0..7
  const int mi   = wv & 1;            // M-tile (32 rows)
  const int ki   = wv >> 1;           // K-split (256 each)

  // ---- stage W_hh[:, n0g:n0g+64] -> ldsW (one-time) ----
  for (int idx = tid; idx < 128 * 64; idx += WGT) {
    int kb = idx >> 6, n = idx & 63;
    unsigned short t[8];
#pragma unroll
    for (int j = 0; j < 8; ++j)
      t[j] = f2bf(W_hh[(size_t)(kb * 8 + j) * Hz + n0g + n]);
    uint4 w;
    w.x = (unsigned)t[0] | ((unsigned)t[1] << 16);
    w.y = (unsigned)t[2] | ((unsigned)t[3] << 16);
    w.z = (unsigned)t[4] | ((unsigned)t[5] << 16);
    w.w = (unsigned)t[6] | ((unsigned)t[7] << 16);
    *(uint4*)&ldsW[(size_t)idx * 8] = w;
  }

  // ---- h0 -> g_hbuf[0] via agent-scope (write-through) stores ----
  for (int idx = tid; idx < (Bz * Hz) / (NWG * 4); idx += WGT) {
    int e = g * (Bz * Hz / NWG) + idx * 4;              // element base (mult of 4)
    unsigned long long v =
        (unsigned long long)f2bf(h0[e]) |
        ((unsigned long long)f2bf(h0[e + 1]) << 16) |
        ((unsigned long long)f2bf(h0[e + 2]) << 32) |
        ((unsigned long long)f2bf(h0[e + 3]) << 48);
    __hip_atomic_store(&g_hbuf[0][e >> 2], v,
                       __ATOMIC_RELAXED, __HIP_MEMORY_SCOPE_AGENT);
  }

  // device barrier: relaxed arrival (stores already write-through + drained by
  // the pre-s_barrier vmcnt(0)); relaxed spin; NO fence (no L2 flush/inv).
  auto barrier = [&](unsigned target) {
    __syncthreads();  // drains each wave's vmem -> h stores visible at L3
    if (tid == 0) {
      __hip_atomic_fetch_add(ctr, 1u, __ATOMIC_RELAXED, __HIP_MEMORY_SCOPE_AGENT);
      while (__hip_atomic_load(ctr, __ATOMIC_RELAXED, __HIP_MEMORY_SCOPE_AGENT) < target)
        __builtin_amdgcn_s_sleep(1);
    }
    __syncthreads();
    asm volatile("" ::: "memory");   // no compiler hoisting across the wait
  };
  barrier(NWG);  // h0 + all W slices staged everywhere

  // epilogue constants: thread -> (batch em, 8 cols at en0)
  const int em  = tid >> 3;          // 0..63
  const int en0 = (tid & 7) * 8;     // 0..56
  float bias[8];
#pragma unroll
  for (int j = 0; j < 8; ++j) bias[j] = b_h[n0g + en0 + j];

  // MFMA fragment address constants (v_mfma_f32_32x32x16_bf16)
  const int am = mi * 32 + (lane & 31);
  const int aq = (lane >> 5) * 8;
  const int bn = lane & 31;
  const unsigned short* hb0 = (const unsigned short*)g_hbuf[0];
  const unsigned short* hb1 = (const unsigned short*)g_hbuf[1];

  // prefetch step-0 token + embedding row
  int tok_n = x[em * Sz];
  float4 xv0_n = *(const float4*)&W_xh[(size_t)tok_n * Hz + n0g + en0];
  float4 xv1_n = *(const float4*)&W_xh[(size_t)tok_n * Hz + n0g + en0 + 4];

  for (int s = 0; s < Sz; ++s) {
    const int p = s & 1;
    const unsigned short* hsrc = p ? hb1 : hb0;

    // coherent prefetch of all 16 A-fragments (512B contiguous per thread)
    uint4 t[16];
    load_afrags(&hsrc[(size_t)am * Hz + ki * 256 + aq], t);
    short8 a[16];
#pragma unroll
    for (int kst = 0; kst < 16; ++kst) a[kst] = *(short8*)&t[kst];

    f32x16 acc0 = {};  // cols [0,32) of slice
    f32x16 acc1 = {};  // cols [32,64)
#pragma unroll
    for (int kst = 0; kst < 16; ++kst) {
      int kb = ki * 32 + kst * 2 + (lane >> 5);
      short8 b0 = *(const short8*)&ldsW[(size_t)(kb * 64 + bn) * 8];
      short8 b1 = *(const short8*)&ldsW[(size_t)(kb * 64 + 32 + bn) * 8];
      acc0 = __builtin_amdgcn_mfma_f32_32x32x16_bf16(a[kst], b0, acc0, 0, 0, 0);
      acc1 = __builtin_amdgcn_mfma_f32_32x32x16_bf16(a[kst], b1, acc1, 0, 0, 0);
    }

    // prefetch NEXT step's token + embedding row (hides gather in reduction)
    float4 xv0 = xv0_n, xv1 = xv1_n;
    if (s + 1 < Sz) {
      int t2 = x[em * Sz + s + 1];
      xv0_n = *(const float4*)&W_xh[(size_t)t2 * Hz + n0g + en0];
      xv1_n = *(const float4*)&W_xh[(size_t)t2 * Hz + n0g + en0 + 4];
    }

    // K-split reduction into red[mi][m][n]
    // C/D: col=lane&31, row=(reg&3)+8*(reg>>2)+4*(lane>>5)  [m74/m101]
    const int crow = 4 * (lane >> 5);
    if (ki == 0) {
#pragma unroll
      for (int r = 0; r < 16; ++r) {
        int m = crow + (r & 3) + 8 * (r >> 2);
        red[mi][m][bn]      = acc0[r];
        red[mi][m][32 + bn] = acc1[r];
      }
    }
    __syncthreads();
    for (int rnd = 1; rnd < 4; ++rnd) {
      if (ki == rnd) {
#pragma unroll
        for (int r = 0; r < 16; ++r) {
          int m = crow + (r & 3) + 8 * (r >> 2);
          red[mi][m][bn]      += acc0[r];
          red[mi][m][32 + bn] += acc1[r];
        }
      }
      __syncthreads();
    }

    // epilogue: z = matmul + emb + bias; h = tanh(z)
    const float* rrow = &red[em >> 5][em & 31][en0];
    float z[8];
    *(float4*)&z[0] = *(const float4*)&rrow[0];
    *(float4*)&z[4] = *(const float4*)&rrow[4];
    z[0] = fast_tanh(z[0] + xv0.x + bias[0]);
    z[1] = fast_tanh(z[1] + xv0.y + bias[1]);
    z[2] = fast_tanh(z[2] + xv0.z + bias[2]);
    z[3] = fast_tanh(z[3] + xv0.w + bias[3]);
    z[4] = fast_tanh(z[4] + xv1.x + bias[4]);
    z[5] = fast_tanh(z[5] + xv1.y + bias[5]);
    z[6] = fast_tanh(z[6] + xv1.z + bias[6]);
    z[7] = fast_tanh(z[7] + xv1.w + bias[7]);

    unsigned pk[4];
#pragma unroll
    for (int j = 0; j < 4; ++j)
      pk[j] = (unsigned)f2bf(z[2 * j]) | ((unsigned)f2bf(z[2 * j + 1]) << 16);

    // h store: agent-scope write-through (visible at L3, no fence needed)
    unsigned long long p0 = (unsigned long long)pk[0] | ((unsigned long long)pk[1] << 32);
    unsigned long long p1 = (unsigned long long)pk[2] | ((unsigned long long)pk[3] << 32);
    int ebase = em * Hz + n0g + en0;                    // element idx (mult of 8)
    __hip_atomic_store(&g_hbuf[p ^ 1][(ebase >> 2)],     p0,
                       __ATOMIC_RELAXED, __HIP_MEMORY_SCOPE_AGENT);
    __hip_atomic_store(&g_hbuf[p ^ 1][(ebase >> 2) + 1], p1,
                       __ATOMIC_RELAXED, __HIP_MEMORY_SCOPE_AGENT);

    // hidden state for phase 2 (plain store; flushed at kernel boundary)
    unsigned short* hidd = g_hidden + ((size_t)em * Sz + s) * Hz + n0g + en0;
    *(uint4*)hidd = *(uint4*)pk;
    if (s == Sz - 1) {
      float* hf = out + (size_t)Bz * Sz * Vz + (size_t)em * Hz + n0g + en0;
      float4 f0 = {z[0], z[1], z[2], z[3]};
      float4 f1 = {z[4], z[5], z[6], z[7]};
      *(float4*)&hf[0] = f0;
      *(float4*)&hf[4] = f1;
    } else {
      barrier((unsigned)NWG * (unsigned)(s + 2));
    }
  }
}

// ---------------- Phase 2: logits = hidden @ W_out + b_out -------------------
__global__ __launch_bounds__(256) void logits_gemm(
    const float* __restrict__ b_out, float* __restrict__ out)
{
  __shared__ unsigned short ldsB[64 * Vz * 8];          // 128 KB: one K-chunk of W_out
  const int tid = threadIdx.x, lane = tid & 63, wv = tid >> 6;
  const int m0 = blockIdx.x * 64 + wv * 16;             // 16 hidden rows per wave
  const unsigned short* arow =
      g_hidden + (size_t)(m0 + (lane & 15)) * Hz + ((lane >> 4) * 8);

  f32x4 acc[8] = {};
  for (int c = 0; c < 2; ++c) {                         // K chunks of 512
    __syncthreads();
    const uint4* src = (const uint4*)&g_wout[(size_t)c * 64 * Vz * 8];
    uint4* dst = (uint4*)ldsB;
    for (int i = tid; i < 8192; i += 256) dst[i] = src[i];
    __syncthreads();

    short8 a[16];
#pragma unroll
    for (int kst = 0; kst < 16; ++kst)
      a[kst] = *(const short8*)&arow[c * 512 + kst * 32];
#pragma unroll
    for (int kst = 0; kst < 16; ++kst) {
      int kb = kst * 4 + (lane >> 4);
#pragma unroll
      for (int nt = 0; nt < 8; ++nt) {
        short8 b = *(const short8*)&ldsB[(size_t)(kb * Vz + nt * 16 + (lane & 15)) * 8];
        acc[nt] = __builtin_amdgcn_mfma_f32_16x16x32_bf16(a[kst], b, acc[nt], 0, 0, 0);
      }
    }
  }
  // C/D: col=lane&15, row=(lane>>4)*4+reg  [m89]
  const int col = lane & 15, q = lane >> 4;
#pragma unroll
  for (int nt = 0; nt < 8; ++nt) {
    float bo = b_out[nt * 16 + col];
#pragma unroll
    for (int r = 0; r < 4; ++r) {
      int m = m0 + q * 4 + r;
      out[(size_t)m * Vz + nt * 16 + col] = acc[nt][r] + bo;
    }
  }
}

// ---------------- host launcher ----------------------------------------------
extern "C" void kernel_launch(void* const* d_in, const int* in_sizes, int n_in,
                              void* d_out, int out_size, void* d_ws, size_t ws_size,
                              hipStream_t stream) {
  const int*   x     = (const int*)d_in[0];
  const float* h0    = (const float*)d_in[1];
  const float* W_xh  = (const float*)d_in[2];
  const float* W_hh  = (const float*)d_in[3];
  const float* b_h   = (const float*)d_in[4];
  const float* W_out = (const float*)d_in[5];
  const float* b_out = (const float*)d_in[6];
  float* out = (float*)d_out;

  (void)hipMemsetAsync(d_ws, 0, 256, stream);              // barrier counter
  pack_wout<<<64, 256, 0, stream>>>(W_out);
  rnn_persistent<<<NWG, WGT, 0, stream>>>(x, h0, W_xh, W_hh, b_h, out,
                                          (unsigned*)d_ws);
  logits_gemm<<<(Bz * Sz) / 64, 256, 0, stream>>>(b_out, out);
}

// Round 5
// 2838.035 us; speedup vs baseline: 1.6446x; 1.6446x over previous
//
#include <hip/hip_runtime.h>
#include <hip/hip_bf16.h>
#include <stdint.h>

// SimpleRNN: B=64, S=512, H=1024, V=128
// Phase 1: persistent 16-wg recurrence, W_hh slice resident in LDS (bf16).
//   h exchanged in MFMA-A-FRAGMENT layout (coalesced both sides) through L3
//   (sc1 loads / sc1 write-through stores); distributed per-wg flag barrier.
// Phase 2: logits GEMM (hidden bf16 @ W_out bf16, fp32 accum) + b_out

#define Bz 64
#define Sz 512
#define Hz 1024
#define Vz 128
#define NWG 16
#define COLS 64   // Hz / NWG columns of W_hh per workgroup
#define WGT 512   // threads per wg (8 waves): 2 M-tiles x 4 K-splits

typedef __attribute__((ext_vector_type(8)))  short short8;
typedef __attribute__((ext_vector_type(16))) float f32x16;
typedef __attribute__((ext_vector_type(4)))  float f32x4;
typedef __attribute__((ext_vector_type(4)))  unsigned u32x4;   // asm-friendly 16B

// h double buffer in MFMA A-fragment order:
// g_hfrag[parity][mi=m>>5][kb=k>>4][lane=((k>>3)&1)*32+(m&31)][j=k&7]
__device__ __align__(16) unsigned short g_hfrag[2][2][64][64][8];   // 2 x 128 KB
__device__ __align__(16) unsigned short g_hidden[(size_t)Bz*Sz*Hz]; // 64 MB, row-major
__device__ __align__(16) unsigned short g_wout[Hz*Vz];              // packed W_out [kb][v][8]

__device__ __forceinline__ unsigned short f2bf(float f) {
  union { float f; unsigned u; } v; v.f = f;
  unsigned r = v.u + 0x7FFFu + ((v.u >> 16) & 1u);      // RNE
  return (unsigned short)(r >> 16);
}

__device__ __forceinline__ float fast_tanh(float x) {
  float cx = fminf(9.0f, fmaxf(-9.0f, x));
  float e  = __builtin_amdgcn_exp2f(cx * 2.88539008178f);   // e^(2x)
  return (e - 1.0f) * __builtin_amdgcn_rcpf(e + 1.0f);
}

// 16 coherent (sc1 -> L3) 16-B loads; each instruction is a fully-coalesced
// 1 KB wave read (lane stride 16 B). Internal vmcnt(0) drain.
__device__ __forceinline__ void load_afrags16(const unsigned short* p0, u32x4 t[16]) {
  const unsigned short* p1 = p0 + 2048;   // +4096 B
  const unsigned short* p2 = p0 + 4096;   // +8192 B
  const unsigned short* p3 = p0 + 6144;   // +12288 B
  asm volatile(
    "global_load_dwordx4 %0,  %16, off sc1\n\t"
    "global_load_dwordx4 %1,  %16, off offset:1024 sc1\n\t"
    "global_load_dwordx4 %2,  %16, off offset:2048 sc1\n\t"
    "global_load_dwordx4 %3,  %16, off offset:3072 sc1\n\t"
    "global_load_dwordx4 %4,  %17, off sc1\n\t"
    "global_load_dwordx4 %5,  %17, off offset:1024 sc1\n\t"
    "global_load_dwordx4 %6,  %17, off offset:2048 sc1\n\t"
    "global_load_dwordx4 %7,  %17, off offset:3072 sc1\n\t"
    "global_load_dwordx4 %8,  %18, off sc1\n\t"
    "global_load_dwordx4 %9,  %18, off offset:1024 sc1\n\t"
    "global_load_dwordx4 %10, %18, off offset:2048 sc1\n\t"
    "global_load_dwordx4 %11, %18, off offset:3072 sc1\n\t"
    "global_load_dwordx4 %12, %19, off sc1\n\t"
    "global_load_dwordx4 %13, %19, off offset:1024 sc1\n\t"
    "global_load_dwordx4 %14, %19, off offset:2048 sc1\n\t"
    "global_load_dwordx4 %15, %19, off offset:3072 sc1\n\t"
    "s_waitcnt vmcnt(0)"
    : "=&v"(t[0]), "=&v"(t[1]), "=&v"(t[2]),  "=&v"(t[3]),
      "=&v"(t[4]), "=&v"(t[5]), "=&v"(t[6]),  "=&v"(t[7]),
      "=&v"(t[8]), "=&v"(t[9]), "=&v"(t[10]), "=&v"(t[11]),
      "=&v"(t[12]),"=&v"(t[13]),"=&v"(t[14]), "=&v"(t[15])
    : "v"(p0), "v"(p1), "v"(p2), "v"(p3)
    : "memory");
}

// agent-scope write-through 16-B store (visible at L3 once vmcnt retires)
__device__ __forceinline__ void store_frag_sc1(unsigned short* p, u32x4 v) {
  asm volatile("global_store_dwordx4 %0, %1, off sc1" :: "v"(p), "v"(v) : "memory");
}

// ---------------- Phase 0: pack W_out (H,V) fp32 -> [kb][v][8] bf16 ----------
__global__ void pack_wout(const float* __restrict__ W_out) {
  int gid = blockIdx.x * blockDim.x + threadIdx.x;      // 0..16383 (kb*128+v)
  int v  = gid & (Vz - 1);
  int kb = gid >> 7;
  unsigned short t[8];
#pragma unroll
  for (int j = 0; j < 8; ++j)
    t[j] = f2bf(W_out[(size_t)(kb * 8 + j) * Vz + v]);
  uint4 w;
  w.x = (unsigned)t[0] | ((unsigned)t[1] << 16);
  w.y = (unsigned)t[2] | ((unsigned)t[3] << 16);
  w.z = (unsigned)t[4] | ((unsigned)t[5] << 16);
  w.w = (unsigned)t[6] | ((unsigned)t[7] << 16);
  *(uint4*)&g_wout[(size_t)gid * 8] = w;
}

// ---------------- Phase 1: persistent recurrence -----------------------------
__global__ __launch_bounds__(WGT) void rnn_persistent(
    const int* __restrict__ x, const float* __restrict__ h0,
    const float* __restrict__ W_xh, const float* __restrict__ W_hh,
    const float* __restrict__ b_h, float* __restrict__ out,
    unsigned* __restrict__ flags)
{
  // W slice, fragment layout [kb8=k/8][n][j] -> conflict-minimal ds_read_b128
  __shared__ unsigned short ldsW[128 * COLS * 8];       // 128 KB
  // 2 K-split partial regions, XOR-swizzled (conflict-free scalar access):
  // float idx = kig*4096 + m*64 + (c ^ (m&31))
  __shared__ float red[2 * 64 * 64];                    // 32 KB

  const int g    = blockIdx.x;        // 0..15
  const int n0g  = g * COLS;          // global column base of this wg's W slice
  const int tid  = threadIdx.x;
  const int lane = tid & 63;
  const int wv   = tid >> 6;          // 0..7
  const int mi   = wv & 1;            // M-tile (32 rows)
  const int ki   = wv >> 1;           // K-split (256 each)

  // ---- stage W_hh[:, n0g:n0g+64] -> ldsW (one-time) ----
  for (int idx = tid; idx < 128 * 64; idx += WGT) {
    int kb = idx >> 6, n = idx & 63;
    unsigned short t[8];
#pragma unroll
    for (int j = 0; j < 8; ++j)
      t[j] = f2bf(W_hh[(size_t)(kb * 8 + j) * Hz + n0g + n]);
    uint4 w;
    w.x = (unsigned)t[0] | ((unsigned)t[1] << 16);
    w.y = (unsigned)t[2] | ((unsigned)t[3] << 16);
    w.z = (unsigned)t[4] | ((unsigned)t[5] << 16);
    w.w = (unsigned)t[6] | ((unsigned)t[7] << 16);
    *(uint4*)&ldsW[(size_t)idx * 8] = w;
  }

  // ---- h0 -> g_hfrag[0] (fragment order); wg g stages slots [g*512, g*512+512) ----
  {
    int s_idx = g * 512 + tid;              // 0..8191 over all wgs
    int fmi = s_idx >> 12, fkb = (s_idx >> 6) & 63, fL = s_idx & 63;
    int m = fmi * 32 + (fL & 31);
    int k = fkb * 16 + (fL >> 5) * 8;
    const float* src = &h0[(size_t)m * Hz + k];
    float4 a0 = *(const float4*)&src[0];
    float4 a1 = *(const float4*)&src[4];
    u32x4 w;
    w.x = (unsigned)f2bf(a0.x) | ((unsigned)f2bf(a0.y) << 16);
    w.y = (unsigned)f2bf(a0.z) | ((unsigned)f2bf(a0.w) << 16);
    w.z = (unsigned)f2bf(a1.x) | ((unsigned)f2bf(a1.y) << 16);
    w.w = (unsigned)f2bf(a1.z) | ((unsigned)f2bf(a1.w) << 16);
    store_frag_sc1(&g_hfrag[0][fmi][fkb][fL][0], w);
  }

  // distributed-flag device barrier:
  //  arrival: tid0 stores step value to its own 64-B line (after all waves'
  //  vmem drained); detection: wave0 lanes 0..15 poll all flags in parallel.
  auto barrier = [&](unsigned target) {
    asm volatile("s_waitcnt vmcnt(0)" ::: "memory");  // drain this wave's stores
    __syncthreads();
    if (tid == 0)
      __hip_atomic_store(&flags[g << 4], target, __ATOMIC_RELAXED,
                         __HIP_MEMORY_SCOPE_AGENT);
    if (wv == 0) {
      for (;;) {
        unsigned v = 0xFFFFFFFFu;
        if (lane < NWG)
          v = __hip_atomic_load(&flags[lane << 4], __ATOMIC_RELAXED,
                                __HIP_MEMORY_SCOPE_AGENT);
        if (__all(v >= target)) break;
        __builtin_amdgcn_s_sleep(1);
      }
    }
    __syncthreads();
    asm volatile("" ::: "memory");
  };
  barrier(1);   // h0 + all W slices staged everywhere

  // epilogue mapping chosen so the h-fragment store is wave-coalesced:
  //   em = (lane&31) + 32*(wv&1);  c0 = (wv>>1)*16 + (lane>>5)*8;  k = n0g+c0
  //   -> fragment slot: mi_t = wv&1, kb = (n0g>>4)+(wv>>1), L = lane  (1 KB/wave)
  const int em  = (lane & 31) + 32 * (wv & 1);
  const int c0  = (wv >> 1) * 16 + (lane >> 5) * 8;
  const int kcol = n0g + c0;
  float bias[8];
#pragma unroll
  for (int j = 0; j < 8; ++j) bias[j] = b_h[kcol + j];

  const int bn = lane & 31;

  // prefetch step-0 token + embedding row
  int tok_n = x[em * Sz];
  float4 xv0_n = *(const float4*)&W_xh[(size_t)tok_n * Hz + kcol];
  float4 xv1_n = *(const float4*)&W_xh[(size_t)tok_n * Hz + kcol + 4];

  for (int s = 0; s < Sz; ++s) {
    const int p = s & 1;

    // coalesced coherent loads of all 16 A-fragments
    u32x4 t[16];
    load_afrags16(&g_hfrag[p][mi][ki * 16][lane][0], t);
    short8 a[16];
#pragma unroll
    for (int kst = 0; kst < 16; ++kst) a[kst] = *(short8*)&t[kst];

    f32x16 acc0 = {};  // cols [0,32) of slice
    f32x16 acc1 = {};  // cols [32,64)
#pragma unroll
    for (int kst = 0; kst < 16; ++kst) {
      int kb8 = ki * 32 + kst * 2 + (lane >> 5);
      short8 b0 = *(const short8*)&ldsW[(size_t)(kb8 * 64 + bn) * 8];
      short8 b1 = *(const short8*)&ldsW[(size_t)(kb8 * 64 + 32 + bn) * 8];
      acc0 = __builtin_amdgcn_mfma_f32_32x32x16_bf16(a[kst], b0, acc0, 0, 0, 0);
      acc1 = __builtin_amdgcn_mfma_f32_32x32x16_bf16(a[kst], b1, acc1, 0, 0, 0);
    }

    // prefetch NEXT step's token + embedding row (hides gather latency)
    float4 xv0 = xv0_n, xv1 = xv1_n;
    if (s + 1 < Sz) {
      int t2 = x[em * Sz + s + 1];
      xv0_n = *(const float4*)&W_xh[(size_t)t2 * Hz + kcol];
      xv1_n = *(const float4*)&W_xh[(size_t)t2 * Hz + kcol + 4];
    }

    // 2-round K-split reduction (XOR-swizzled, conflict-free)
    // C/D: col=lane&31, row=(reg&3)+8*(reg>>2)+4*(lane>>5)  [m74/m101]
    const int crow = 4 * (lane >> 5);
    if (ki < 2) {
      float* reg = &red[ki * 4096];
#pragma unroll
      for (int r = 0; r < 16; ++r) {
        int m = mi * 32 + crow + (r & 3) + 8 * (r >> 2);
        reg[m * 64 + ((bn)      ^ (m & 31))] = acc0[r];
        reg[m * 64 + ((32 + bn) ^ (m & 31))] = acc1[r];
      }
    }
    __syncthreads();
    if (ki >= 2) {
      float* reg = &red[(ki - 2) * 4096];
#pragma unroll
      for (int r = 0; r < 16; ++r) {
        int m = mi * 32 + crow + (r & 3) + 8 * (r >> 2);
        reg[m * 64 + ((bn)      ^ (m & 31))] += acc0[r];
        reg[m * 64 + ((32 + bn) ^ (m & 31))] += acc1[r];
      }
    }
    __syncthreads();

    // epilogue: z = partial0 + partial1 + emb + bias; h = tanh(z)
    float z[8];
    {
      const float* r0 = &red[em * 64];
      const float* r1 = &red[4096 + em * 64];
      const int sw = em & 31;
#pragma unroll
      for (int j = 0; j < 8; ++j)
        z[j] = r0[(c0 + j) ^ sw] + r1[(c0 + j) ^ sw];
    }
    z[0] = fast_tanh(z[0] + xv0.x + bias[0]);
    z[1] = fast_tanh(z[1] + xv0.y + bias[1]);
    z[2] = fast_tanh(z[2] + xv0.z + bias[2]);
    z[3] = fast_tanh(z[3] + xv0.w + bias[3]);
    z[4] = fast_tanh(z[4] + xv1.x + bias[4]);
    z[5] = fast_tanh(z[5] + xv1.y + bias[5]);
    z[6] = fast_tanh(z[6] + xv1.z + bias[6]);
    z[7] = fast_tanh(z[7] + xv1.w + bias[7]);

    u32x4 w;
    w.x = (unsigned)f2bf(z[0]) | ((unsigned)f2bf(z[1]) << 16);
    w.y = (unsigned)f2bf(z[2]) | ((unsigned)f2bf(z[3]) << 16);
    w.z = (unsigned)f2bf(z[4]) | ((unsigned)f2bf(z[5]) << 16);
    w.w = (unsigned)f2bf(z[6]) | ((unsigned)f2bf(z[7]) << 16);

    // h store: fragment layout, wave-coalesced (1 KB/wave), write-through
    store_frag_sc1(&g_hfrag[p ^ 1][wv & 1][(n0g >> 4) + (wv >> 1)][lane][0], w);

    // hidden state for phase 2 (row-major, plain store)
    *(u32x4*)&g_hidden[((size_t)em * Sz + s) * Hz + kcol] = w;

    if (s == Sz - 1) {
      float* hf = out + (size_t)Bz * Sz * Vz + (size_t)em * Hz + kcol;
      float4 f0 = {z[0], z[1], z[2], z[3]};
      float4 f1 = {z[4], z[5], z[6], z[7]};
      *(float4*)&hf[0] = f0;
      *(float4*)&hf[4] = f1;
    } else {
      barrier((unsigned)(s + 2));
    }
  }
}

// ---------------- Phase 2: logits = hidden @ W_out + b_out -------------------
__global__ __launch_bounds__(256) void logits_gemm(
    const float* __restrict__ b_out, float* __restrict__ out)
{
  __shared__ unsigned short ldsB[64 * Vz * 8];          // 128 KB: one K-chunk of W_out
  const int tid = threadIdx.x, lane = tid & 63, wv = tid >> 6;
  const int m0 = blockIdx.x * 64 + wv * 16;             // 16 hidden rows per wave
  const unsigned short* arow =
      g_hidden + (size_t)(m0 + (lane & 15)) * Hz + ((lane >> 4) * 8);

  f32x4 acc[8] = {};
  for (int c = 0; c < 2; ++c) {                         // K chunks of 512
    __syncthreads();
    const uint4* src = (const uint4*)&g_wout[(size_t)c * 64 * Vz * 8];
    uint4* dst = (uint4*)ldsB;
    for (int i = tid; i < 8192; i += 256) dst[i] = src[i];
    __syncthreads();

    short8 a[16];
#pragma unroll
    for (int kst = 0; kst < 16; ++kst)
      a[kst] = *(const short8*)&arow[c * 512 + kst * 32];
#pragma unroll
    for (int kst = 0; kst < 16; ++kst) {
      int kb = kst * 4 + (lane >> 4);
#pragma unroll
      for (int nt = 0; nt < 8; ++nt) {
        short8 b = *(const short8*)&ldsB[(size_t)(kb * Vz + nt * 16 + (lane & 15)) * 8];
        acc[nt] = __builtin_amdgcn_mfma_f32_16x16x32_bf16(a[kst], b, acc[nt], 0, 0, 0);
      }
    }
  }
  // C/D: col=lane&15, row=(lane>>4)*4+reg  [m89]
  const int col = lane & 15, q = lane >> 4;
#pragma unroll
  for (int nt = 0; nt < 8; ++nt) {
    float bo = b_out[nt * 16 + col];
#pragma unroll
    for (int r = 0; r < 4; ++r) {
      int m = m0 + q * 4 + r;
      out[(size_t)m * Vz + nt * 16 + col] = acc[nt][r] + bo;
    }
  }
}

// ---------------- host launcher ----------------------------------------------
extern "C" void kernel_launch(void* const* d_in, const int* in_sizes, int n_in,
                              void* d_out, int out_size, void* d_ws, size_t ws_size,
                              hipStream_t stream) {
  const int*   x     = (const int*)d_in[0];
  const float* h0    = (const float*)d_in[1];
  const float* W_xh  = (const float*)d_in[2];
  const float* W_hh  = (const float*)d_in[3];
  const float* b_h   = (const float*)d_in[4];
  const float* W_out = (const float*)d_in[5];
  const float* b_out = (const float*)d_in[6];
  float* out = (float*)d_out;

  (void)hipMemsetAsync(d_ws, 0, 1024, stream);             // 16 flag lines
  pack_wout<<<64, 256, 0, stream>>>(W_out);
  rnn_persistent<<<NWG, WGT, 0, stream>>>(x, h0, W_xh, W_hh, b_h, out,
                                          (unsigned*)d_ws);
  logits_gemm<<<(Bz * Sz) / 64, 256, 0, stream>>>(b_out, out);
}

// Round 8
// 2449.231 us; speedup vs baseline: 1.9057x; 1.1587x over previous
//
#include <hip/hip_runtime.h>
#include <hip/hip_bf16.h>
#include <stdint.h>

// SimpleRNN: B=64, S=512, H=1024, V=128
// Phase 1: persistent 16-wg recurrence, W_hh slice resident in LDS (bf16).
//   h exchanged in MFMA-A-FRAGMENT layout (coalesced both sides) through L3
//   (sc1 loads / sc1 write-through stores); R5-PROVEN per-wg flag barrier
//   (bounded spin: a protocol bug degrades to wrong answer, never a hang).
//   Hidden states stored in fragment layout too (no partial-line RFO).
// Phase 2: logits GEMM (hidden bf16 @ W_out bf16, 32x32x16 MFMA) + b_out

#define Bz 64
#define Sz 512
#define Hz 1024
#define Vz 128
#define NWG 16
#define COLS 64   // Hz / NWG columns of W_hh per workgroup
#define WGT 512   // threads per wg (8 waves): 2 M-tiles x 4 K-splits

typedef __attribute__((ext_vector_type(8)))  short short8;
typedef __attribute__((ext_vector_type(16))) float f32x16;
typedef __attribute__((ext_vector_type(4)))  unsigned u32x4;   // asm-friendly 16B

// h double buffer in MFMA A-fragment order:
// g_hfrag[parity][mi=m>>5][kb=k>>4][lane=((k>>3)&1)*32+(m&31)][j=k&7]
__device__ __align__(16) unsigned short g_hfrag[2][2][64][64][8];   // 2 x 128 KB
// hidden states, fragment order per step: [s][mi][kb][lane][8]  (64 MB)
__device__ __align__(16) unsigned short g_hidden[(size_t)Sz*2*64*64*8];
// W_out packed for 32x32x16 B-frags: [kb][nt][lane][8]  (256 KB)
__device__ __align__(16) unsigned short g_wout[64*4*64*8];

__device__ __forceinline__ unsigned short f2bf(float f) {
  union { float f; unsigned u; } v; v.f = f;
  unsigned r = v.u + 0x7FFFu + ((v.u >> 16) & 1u);      // RNE
  return (unsigned short)(r >> 16);
}

__device__ __forceinline__ float fast_tanh(float x) {
  float cx = fminf(9.0f, fmaxf(-9.0f, x));
  float e  = __builtin_amdgcn_exp2f(cx * 2.88539008178f);   // e^(2x)
  return (e - 1.0f) * __builtin_amdgcn_rcpf(e + 1.0f);
}

// 16 coherent (sc1 -> L3) 16-B loads; each instruction is a fully-coalesced
// 1 KB wave read (lane stride 16 B). Internal vmcnt(0) drain.
__device__ __forceinline__ void load_afrags16(const unsigned short* p0, u32x4 t[16]) {
  const unsigned short* p1 = p0 + 2048;   // +4096 B
  const unsigned short* p2 = p0 + 4096;   // +8192 B
  const unsigned short* p3 = p0 + 6144;   // +12288 B
  asm volatile(
    "global_load_dwordx4 %0,  %16, off sc1\n\t"
    "global_load_dwordx4 %1,  %16, off offset:1024 sc1\n\t"
    "global_load_dwordx4 %2,  %16, off offset:2048 sc1\n\t"
    "global_load_dwordx4 %3,  %16, off offset:3072 sc1\n\t"
    "global_load_dwordx4 %4,  %17, off sc1\n\t"
    "global_load_dwordx4 %5,  %17, off offset:1024 sc1\n\t"
    "global_load_dwordx4 %6,  %17, off offset:2048 sc1\n\t"
    "global_load_dwordx4 %7,  %17, off offset:3072 sc1\n\t"
    "global_load_dwordx4 %8,  %18, off sc1\n\t"
    "global_load_dwordx4 %9,  %18, off offset:1024 sc1\n\t"
    "global_load_dwordx4 %10, %18, off offset:2048 sc1\n\t"
    "global_load_dwordx4 %11, %18, off offset:3072 sc1\n\t"
    "global_load_dwordx4 %12, %19, off sc1\n\t"
    "global_load_dwordx4 %13, %19, off offset:1024 sc1\n\t"
    "global_load_dwordx4 %14, %19, off offset:2048 sc1\n\t"
    "global_load_dwordx4 %15, %19, off offset:3072 sc1\n\t"
    "s_waitcnt vmcnt(0)"
    : "=&v"(t[0]), "=&v"(t[1]), "=&v"(t[2]),  "=&v"(t[3]),
      "=&v"(t[4]), "=&v"(t[5]), "=&v"(t[6]),  "=&v"(t[7]),
      "=&v"(t[8]), "=&v"(t[9]), "=&v"(t[10]), "=&v"(t[11]),
      "=&v"(t[12]),"=&v"(t[13]),"=&v"(t[14]), "=&v"(t[15])
    : "v"(p0), "v"(p1), "v"(p2), "v"(p3)
    : "memory");
}

// agent-scope write-through 16-B store (visible at L3 once vmcnt retires)
__device__ __forceinline__ void store_frag_sc1(unsigned short* p, u32x4 v) {
  asm volatile("global_store_dwordx4 %0, %1, off sc1" :: "v"(p), "v"(v) : "memory");
}

// ---- Phase 0: pack W_out (H,V) fp32 -> [kb][nt][lane][8] bf16 (32x32 B-frag) --
__global__ void pack_wout(const float* __restrict__ W_out) {
  int gid = blockIdx.x * blockDim.x + threadIdx.x;      // 0..16383
  int lane = gid & 63;
  int nt   = (gid >> 6) & 3;
  int kb   = gid >> 8;
  int n = nt * 32 + (lane & 31);
  int k0 = kb * 16 + (lane >> 5) * 8;
  unsigned short t[8];
#pragma unroll
  for (int j = 0; j < 8; ++j)
    t[j] = f2bf(W_out[(size_t)(k0 + j) * Vz + n]);
  uint4 w;
  w.x = (unsigned)t[0] | ((unsigned)t[1] << 16);
  w.y = (unsigned)t[2] | ((unsigned)t[3] << 16);
  w.z = (unsigned)t[4] | ((unsigned)t[5] << 16);
  w.w = (unsigned)t[6] | ((unsigned)t[7] << 16);
  *(uint4*)&g_wout[(size_t)gid * 8] = w;
}

// ---------------- Phase 1: persistent recurrence -----------------------------
__global__ __launch_bounds__(WGT) void rnn_persistent(
    const int* __restrict__ x, const float* __restrict__ h0,
    const float* __restrict__ W_xh, const float* __restrict__ W_hh,
    const float* __restrict__ b_h, float* __restrict__ out,
    unsigned* __restrict__ flags)
{
  // W slice, fragment layout [kb8=k/8][n][j] -> conflict-minimal ds_read_b128
  __shared__ unsigned short ldsW[128 * COLS * 8];       // 128 KB
  // 2 K-split partial regions, XOR-swizzled (conflict-free scalar access)
  __shared__ float red[2 * 64 * 64];                    // 32 KB

  const int g    = blockIdx.x;        // 0..15
  const int n0g  = g * COLS;          // global column base of this wg's W slice
  const int tid  = threadIdx.x;
  const int lane = tid & 63;
  const int wv   = tid >> 6;          // 0..7
  const int mi   = wv & 1;            // M-tile (32 rows)
  const int ki   = wv >> 1;           // K-split (256 each)

  // ---- stage W_hh[:, n0g:n0g+64] -> ldsW (one-time) ----
  for (int idx = tid; idx < 128 * 64; idx += WGT) {
    int kb = idx >> 6, n = idx & 63;
    unsigned short t[8];
#pragma unroll
    for (int j = 0; j < 8; ++j)
      t[j] = f2bf(W_hh[(size_t)(kb * 8 + j) * Hz + n0g + n]);
    uint4 w;
    w.x = (unsigned)t[0] | ((unsigned)t[1] << 16);
    w.y = (unsigned)t[2] | ((unsigned)t[3] << 16);
    w.z = (unsigned)t[4] | ((unsigned)t[5] << 16);
    w.w = (unsigned)t[6] | ((unsigned)t[7] << 16);
    *(uint4*)&ldsW[(size_t)idx * 8] = w;
  }

  // ---- h0 -> g_hfrag[0] (fragment order); wg g stages slots [g*512, g*512+512) ----
  {
    int s_idx = g * 512 + tid;              // 0..8191 over all wgs
    int fmi = s_idx >> 12, fkb = (s_idx >> 6) & 63, fL = s_idx & 63;
    int m = fmi * 32 + (fL & 31);
    int k = fkb * 16 + (fL >> 5) * 8;
    const float* src = &h0[(size_t)m * Hz + k];
    float4 a0 = *(const float4*)&src[0];
    float4 a1 = *(const float4*)&src[4];
    u32x4 w;
    w.x = (unsigned)f2bf(a0.x) | ((unsigned)f2bf(a0.y) << 16);
    w.y = (unsigned)f2bf(a0.z) | ((unsigned)f2bf(a0.w) << 16);
    w.z = (unsigned)f2bf(a1.x) | ((unsigned)f2bf(a1.y) << 16);
    w.w = (unsigned)f2bf(a1.z) | ((unsigned)f2bf(a1.w) << 16);
    store_frag_sc1(&g_hfrag[0][fmi][fkb][fL][0], w);
  }

  // R5-PROVEN distributed-flag device barrier (per-WG flag lines in d_ws):
  //  arrival: __syncthreads (drains each wave's vmem before s_barrier) then
  //  tid0 stores the step value to its own 64-B line; detection: wave0 lanes
  //  0..15 poll all 16 flags in parallel. Spin is BOUNDED: on timeout we fall
  //  through (possible wrong answer, never a hang).
  auto barrier = [&](unsigned target) {
    __syncthreads();
    if (tid == 0)
      __hip_atomic_store(&flags[g << 4], target, __ATOMIC_RELAXED,
                         __HIP_MEMORY_SCOPE_AGENT);
    if (wv == 0) {
      for (int it = 0; it < 65536; ++it) {
        unsigned v = 0xFFFFFFFFu;
        if (lane < NWG)
          v = __hip_atomic_load(&flags[lane << 4], __ATOMIC_RELAXED,
                                __HIP_MEMORY_SCOPE_AGENT);
        if (__all(v >= target)) break;
        __builtin_amdgcn_s_sleep(1);
      }
    }
    __syncthreads();
    asm volatile("" ::: "memory");
  };
  barrier(1);   // h0 + all W slices staged everywhere

  // epilogue mapping (h-fragment store wave-coalesced):
  //   em = (lane&31) + 32*(wv&1);  c0 = (wv>>1)*16 + (lane>>5)*8;  k = n0g+c0
  //   -> fragment slot: mi_t = wv&1, kb = (n0g>>4)+(wv>>1), L = lane  (1 KB/wave)
  const int em  = (lane & 31) + 32 * (wv & 1);
  const int c0  = (wv >> 1) * 16 + (lane >> 5) * 8;
  const int kcol = n0g + c0;
  const int slot = ((wv & 1) * 64 + (n0g >> 4) + (wv >> 1)) * 64 + lane;  // frag slot idx
  float bias[8];
#pragma unroll
  for (int j = 0; j < 8; ++j) bias[j] = b_h[kcol + j];

  const int bn = lane & 31;

  // prefetch step-0 token + embedding row
  int tok_n = x[em * Sz];
  float4 xv0_n = *(const float4*)&W_xh[(size_t)tok_n * Hz + kcol];
  float4 xv1_n = *(const float4*)&W_xh[(size_t)tok_n * Hz + kcol + 4];

  for (int s = 0; s < Sz; ++s) {
    const int p = s & 1;

    // coalesced coherent loads of all 16 A-fragments
    u32x4 t[16];
    load_afrags16(&g_hfrag[p][mi][ki * 16][lane][0], t);
    short8 a[16];
#pragma unroll
    for (int kst = 0; kst < 16; ++kst) a[kst] = *(short8*)&t[kst];

    f32x16 acc0 = {};  // cols [0,32) of slice
    f32x16 acc1 = {};  // cols [32,64)
#pragma unroll
    for (int kst = 0; kst < 16; ++kst) {
      int kb8 = ki * 32 + kst * 2 + (lane >> 5);
      short8 b0 = *(const short8*)&ldsW[(size_t)(kb8 * 64 + bn) * 8];
      short8 b1 = *(const short8*)&ldsW[(size_t)(kb8 * 64 + 32 + bn) * 8];
      acc0 = __builtin_amdgcn_mfma_f32_32x32x16_bf16(a[kst], b0, acc0, 0, 0, 0);
      acc1 = __builtin_amdgcn_mfma_f32_32x32x16_bf16(a[kst], b1, acc1, 0, 0, 0);
    }

    // prefetch NEXT step's token + embedding row (hides gather latency)
    float4 xv0 = xv0_n, xv1 = xv1_n;
    if (s + 1 < Sz) {
      int t2 = x[em * Sz + s + 1];
      xv0_n = *(const float4*)&W_xh[(size_t)t2 * Hz + kcol];
      xv1_n = *(const float4*)&W_xh[(size_t)t2 * Hz + kcol + 4];
    }

    // 2-round K-split reduction (XOR-swizzled, conflict-free)
    // C/D: col=lane&31, row=(reg&3)+8*(reg>>2)+4*(lane>>5)  [m74/m101]
    const int crow = 4 * (lane >> 5);
    if (ki < 2) {
      float* reg = &red[ki * 4096];
#pragma unroll
      for (int r = 0; r < 16; ++r) {
        int m = mi * 32 + crow + (r & 3) + 8 * (r >> 2);
        reg[m * 64 + ((bn)      ^ (m & 31))] = acc0[r];
        reg[m * 64 + ((32 + bn) ^ (m & 31))] = acc1[r];
      }
    }
    __syncthreads();
    if (ki >= 2) {
      float* reg = &red[(ki - 2) * 4096];
#pragma unroll
      for (int r = 0; r < 16; ++r) {
        int m = mi * 32 + crow + (r & 3) + 8 * (r >> 2);
        reg[m * 64 + ((bn)      ^ (m & 31))] += acc0[r];
        reg[m * 64 + ((32 + bn) ^ (m & 31))] += acc1[r];
      }
    }
    __syncthreads();

    // epilogue: z = partial0 + partial1 + emb + bias; h = tanh(z)
    float z[8];
    {
      const float* r0 = &red[em * 64];
      const float* r1 = &red[4096 + em * 64];
      const int sw = em & 31;
#pragma unroll
      for (int j = 0; j < 8; ++j)
        z[j] = r0[(c0 + j) ^ sw] + r1[(c0 + j) ^ sw];
    }
    z[0] = fast_tanh(z[0] + xv0.x + bias[0]);
    z[1] = fast_tanh(z[1] + xv0.y + bias[1]);
    z[2] = fast_tanh(z[2] + xv0.z + bias[2]);
    z[3] = fast_tanh(z[3] + xv0.w + bias[3]);
    z[4] = fast_tanh(z[4] + xv1.x + bias[4]);
    z[5] = fast_tanh(z[5] + xv1.y + bias[5]);
    z[6] = fast_tanh(z[6] + xv1.z + bias[6]);
    z[7] = fast_tanh(z[7] + xv1.w + bias[7]);

    u32x4 w;
    w.x = (unsigned)f2bf(z[0]) | ((unsigned)f2bf(z[1]) << 16);
    w.y = (unsigned)f2bf(z[2]) | ((unsigned)f2bf(z[3]) << 16);
    w.z = (unsigned)f2bf(z[4]) | ((unsigned)f2bf(z[5]) << 16);
    w.w = (unsigned)f2bf(z[6]) | ((unsigned)f2bf(z[7]) << 16);

    // h store: fragment layout, wave-coalesced (1 KB/wave), write-through
    store_frag_sc1(&((unsigned short*)g_hfrag)[((size_t)(p ^ 1) * 8192 + slot) * 8], w);
    // hidden state, SAME fragment layout per step (coalesced, no RFO)
    *(u32x4*)&g_hidden[((size_t)s * 8192 + slot) * 8] = w;

    if (s == Sz - 1) {
      float* hf = out + (size_t)Bz * Sz * Vz + (size_t)em * Hz + kcol;
      float4 f0 = {z[0], z[1], z[2], z[3]};
      float4 f1 = {z[4], z[5], z[6], z[7]};
      *(float4*)&hf[0] = f0;
      *(float4*)&hf[4] = f1;
    } else {
      barrier((unsigned)(s + 2));
    }
  }
}

// ---------------- Phase 2: logits = hidden @ W_out + b_out -------------------
// grid: 1024 blocks = (s, mi); 4 waves; wave nt computes 32 rows x 32 cols, K=1024
__global__ __launch_bounds__(256) void logits_gemm(
    const float* __restrict__ b_out, float* __restrict__ out)
{
  const int tid = threadIdx.x, lane = tid & 63, nt = tid >> 6;
  const int s = blockIdx.x >> 1, mi = blockIdx.x & 1;
  const unsigned short* ab = &g_hidden[((size_t)s * 8192 + (size_t)mi * 4096) * 8];

  f32x16 acc = {};
#pragma unroll 8
  for (int kb = 0; kb < 64; ++kb) {
    short8 a = *(const short8*)&ab[(size_t)(kb * 64 + lane) * 8];
    short8 b = *(const short8*)&g_wout[(size_t)((kb * 4 + nt) * 64 + lane) * 8];
    acc = __builtin_amdgcn_mfma_f32_32x32x16_bf16(a, b, acc, 0, 0, 0);
  }
  const int col = nt * 32 + (lane & 31);
  const float bo = b_out[col];
  const int rbase = 4 * (lane >> 5);
#pragma unroll
  for (int r = 0; r < 16; ++r) {
    int m = rbase + (r & 3) + 8 * (r >> 2);
    int em = mi * 32 + m;
    out[((size_t)em * Sz + s) * Vz + col] = acc[r] + bo;
  }
}

// ---------------- host launcher ----------------------------------------------
extern "C" void kernel_launch(void* const* d_in, const int* in_sizes, int n_in,
                              void* d_out, int out_size, void* d_ws, size_t ws_size,
                              hipStream_t stream) {
  const int*   x     = (const int*)d_in[0];
  const float* h0    = (const float*)d_in[1];
  const float* W_xh  = (const float*)d_in[2];
  const float* W_hh  = (const float*)d_in[3];
  const float* b_h   = (const float*)d_in[4];
  const float* W_out = (const float*)d_in[5];
  const float* b_out = (const float*)d_in[6];
  float* out = (float*)d_out;

  (void)hipMemsetAsync(d_ws, 0, 1024, stream);             // 16 wg-flag lines (R5-proven)
  pack_wout<<<64, 256, 0, stream>>>(W_out);
  rnn_persistent<<<NWG, WGT, 0, stream>>>(x, h0, W_xh, W_hh, b_h, out,
                                          (unsigned*)d_ws);
  logits_gemm<<<Sz * 2, 256, 0, stream>>>(b_out, out);
}

// Round 11
// 2110.961 us; speedup vs baseline: 2.2111x; 1.1602x over previous
//
#include <hip/hip_runtime.h>
#include <hip/hip_bf16.h>
#include <stdint.h>

// SimpleRNN: B=64, S=512, H=1024, V=128
// Phase 1: persistent 16-wg recurrence (R8-PROVEN protocol: grid=16, per-wg
//   flag barrier in d_ws, sc1 h-exchange in MFMA A-fragment layout).
//   NEW vs R8 (intra-wg only): W_hh cols[0,32) in REGISTERS / cols[32,64) in
//   LDS; single-sync 4-region K-split reduction; g_hidden store overlapped
//   with flag propagation.
// Phase 2: logits GEMM (hidden bf16 @ W_out bf16, 32x32x16 MFMA) + b_out

#define Bz 64
#define Sz 512
#define Hz 1024
#define Vz 128
#define NWG 16
#define COLS 64   // Hz / NWG columns of W_hh per workgroup
#define WGT 512   // threads per wg (8 waves): 2 M-tiles x 4 K-splits

typedef __attribute__((ext_vector_type(8)))  short short8;
typedef __attribute__((ext_vector_type(16))) float f32x16;
typedef __attribute__((ext_vector_type(4)))  unsigned u32x4;   // asm-friendly 16B

// h double buffer in MFMA A-fragment order:
// g_hfrag[parity][mi=m>>5][kb=k>>4][lane=((k>>3)&1)*32+(m&31)][j=k&7]
__device__ __align__(16) unsigned short g_hfrag[2][2][64][64][8];   // 2 x 128 KB
// hidden states, fragment order per step: [s][mi][kb][lane][8]  (64 MB)
__device__ __align__(16) unsigned short g_hidden[(size_t)Sz*2*64*64*8];
// W_out packed for 32x32x16 B-frags: [kb][nt][lane][8]  (256 KB)
__device__ __align__(16) unsigned short g_wout[64*4*64*8];

__device__ __forceinline__ unsigned short f2bf(float f) {
  union { float f; unsigned u; } v; v.f = f;
  unsigned r = v.u + 0x7FFFu + ((v.u >> 16) & 1u);      // RNE
  return (unsigned short)(r >> 16);
}

__device__ __forceinline__ float fast_tanh(float x) {
  float cx = fminf(9.0f, fmaxf(-9.0f, x));
  float e  = __builtin_amdgcn_exp2f(cx * 2.88539008178f);   // e^(2x)
  return (e - 1.0f) * __builtin_amdgcn_rcpf(e + 1.0f);
}

// 16 coherent (sc1 -> L3) 16-B loads; each instruction is a fully-coalesced
// 1 KB wave read (lane stride 16 B). Internal vmcnt(0) drain.  [R8-proven]
__device__ __forceinline__ void load_afrags16(const unsigned short* p0, u32x4 t[16]) {
  const unsigned short* p1 = p0 + 2048;   // +4096 B
  const unsigned short* p2 = p0 + 4096;   // +8192 B
  const unsigned short* p3 = p0 + 6144;   // +12288 B
  asm volatile(
    "global_load_dwordx4 %0,  %16, off sc1\n\t"
    "global_load_dwordx4 %1,  %16, off offset:1024 sc1\n\t"
    "global_load_dwordx4 %2,  %16, off offset:2048 sc1\n\t"
    "global_load_dwordx4 %3,  %16, off offset:3072 sc1\n\t"
    "global_load_dwordx4 %4,  %17, off sc1\n\t"
    "global_load_dwordx4 %5,  %17, off offset:1024 sc1\n\t"
    "global_load_dwordx4 %6,  %17, off offset:2048 sc1\n\t"
    "global_load_dwordx4 %7,  %17, off offset:3072 sc1\n\t"
    "global_load_dwordx4 %8,  %18, off sc1\n\t"
    "global_load_dwordx4 %9,  %18, off offset:1024 sc1\n\t"
    "global_load_dwordx4 %10, %18, off offset:2048 sc1\n\t"
    "global_load_dwordx4 %11, %18, off offset:3072 sc1\n\t"
    "global_load_dwordx4 %12, %19, off sc1\n\t"
    "global_load_dwordx4 %13, %19, off offset:1024 sc1\n\t"
    "global_load_dwordx4 %14, %19, off offset:2048 sc1\n\t"
    "global_load_dwordx4 %15, %19, off offset:3072 sc1\n\t"
    "s_waitcnt vmcnt(0)"
    : "=&v"(t[0]), "=&v"(t[1]), "=&v"(t[2]),  "=&v"(t[3]),
      "=&v"(t[4]), "=&v"(t[5]), "=&v"(t[6]),  "=&v"(t[7]),
      "=&v"(t[8]), "=&v"(t[9]), "=&v"(t[10]), "=&v"(t[11]),
      "=&v"(t[12]),"=&v"(t[13]),"=&v"(t[14]), "=&v"(t[15])
    : "v"(p0), "v"(p1), "v"(p2), "v"(p3)
    : "memory");
}

// agent-scope write-through 16-B store (visible at L3 once vmcnt retires)
__device__ __forceinline__ void store_frag_sc1(unsigned short* p, u32x4 v) {
  asm volatile("global_store_dwordx4 %0, %1, off sc1" :: "v"(p), "v"(v) : "memory");
}

// ---- Phase 0: pack W_out (H,V) fp32 -> [kb][nt][lane][8] bf16 (32x32 B-frag) --
__global__ void pack_wout(const float* __restrict__ W_out) {
  int gid = blockIdx.x * blockDim.x + threadIdx.x;      // 0..16383
  int lane = gid & 63;
  int nt   = (gid >> 6) & 3;
  int kb   = gid >> 8;
  int n = nt * 32 + (lane & 31);
  int k0 = kb * 16 + (lane >> 5) * 8;
  unsigned short t[8];
#pragma unroll
  for (int j = 0; j < 8; ++j)
    t[j] = f2bf(W_out[(size_t)(k0 + j) * Vz + n]);
  uint4 w;
  w.x = (unsigned)t[0] | ((unsigned)t[1] << 16);
  w.y = (unsigned)t[2] | ((unsigned)t[3] << 16);
  w.z = (unsigned)t[4] | ((unsigned)t[5] << 16);
  w.w = (unsigned)t[6] | ((unsigned)t[7] << 16);
  *(uint4*)&g_wout[(size_t)gid * 8] = w;
}

// ---------------- Phase 1: persistent recurrence -----------------------------
__global__ __launch_bounds__(WGT) void rnn_persistent(
    const int* __restrict__ x, const float* __restrict__ h0,
    const float* __restrict__ W_xh, const float* __restrict__ W_hh,
    const float* __restrict__ b_h, float* __restrict__ out,
    unsigned* __restrict__ flags)
{
  // W slice cols [32,64): fragment layout [kb8][n32][j] -> ds_read_b128
  __shared__ unsigned short ldsW1[128 * 32 * 8];        // 64 KB
  // 4 K-split partial regions, XOR-swizzled: red[ki*4096 + m*64 + (c^(m&31))]
  __shared__ float red[4 * 64 * 64];                    // 64 KB

  const int g    = blockIdx.x;        // 0..15
  const int n0g  = g * COLS;          // global column base of this wg's W slice
  const int tid  = threadIdx.x;
  const int lane = tid & 63;
  const int wv   = tid >> 6;          // 0..7
  const int mi   = wv & 1;            // M-tile (32 rows)
  const int ki   = wv >> 1;           // K-split (256 each)
  const int bn   = lane & 31;

  // ---- stage W_hh[:, n0g+32 : n0g+64) -> ldsW1 (one-time) ----
  for (int idx = tid; idx < 128 * 32; idx += WGT) {
    int kb = idx >> 5, n = idx & 31;
    unsigned short t[8];
#pragma unroll
    for (int j = 0; j < 8; ++j)
      t[j] = f2bf(W_hh[(size_t)(kb * 8 + j) * Hz + n0g + 32 + n]);
    uint4 w;
    w.x = (unsigned)t[0] | ((unsigned)t[1] << 16);
    w.y = (unsigned)t[2] | ((unsigned)t[3] << 16);
    w.z = (unsigned)t[4] | ((unsigned)t[5] << 16);
    w.w = (unsigned)t[6] | ((unsigned)t[7] << 16);
    *(uint4*)&ldsW1[(size_t)idx * 8] = w;
  }

  // ---- stage W_hh[:, n0g : n0g+32) -> REGISTERS (one-time, per wave ki) ----
  // b0r[kst][j] = W_hh[k = (ki*32 + kst*2 + (lane>>5))*8 + j][n0g + bn]
  short8 b0r[16];
#pragma unroll
  for (int kst = 0; kst < 16; ++kst) {
    const float* wrow = &W_hh[(size_t)((ki * 32 + kst * 2 + (lane >> 5)) * 8) * Hz
                              + n0g + bn];
#pragma unroll
    for (int j = 0; j < 8; ++j)
      b0r[kst][j] = (short)f2bf(wrow[(size_t)j * Hz]);
  }

  // ---- h0 -> g_hfrag[0] (fragment order); wg g stages slots [g*512, g*512+512) ----
  {
    int s_idx = g * 512 + tid;              // 0..8191 over all wgs
    int fmi = s_idx >> 12, fkb = (s_idx >> 6) & 63, fL = s_idx & 63;
    int m = fmi * 32 + (fL & 31);
    int k = fkb * 16 + (fL >> 5) * 8;
    const float* src = &h0[(size_t)m * Hz + k];
    float4 a0 = *(const float4*)&src[0];
    float4 a1 = *(const float4*)&src[4];
    u32x4 w;
    w.x = (unsigned)f2bf(a0.x) | ((unsigned)f2bf(a0.y) << 16);
    w.y = (unsigned)f2bf(a0.z) | ((unsigned)f2bf(a0.w) << 16);
    w.z = (unsigned)f2bf(a1.x) | ((unsigned)f2bf(a1.y) << 16);
    w.w = (unsigned)f2bf(a1.z) | ((unsigned)f2bf(a1.w) << 16);
    store_frag_sc1(&g_hfrag[0][fmi][fkb][fL][0], w);
  }

  // R8-PROVEN distributed-flag device barrier (per-WG flag lines in d_ws).
  auto barrier = [&](unsigned target) {
    __syncthreads();
    if (tid == 0)
      __hip_atomic_store(&flags[g << 4], target, __ATOMIC_RELAXED,
                         __HIP_MEMORY_SCOPE_AGENT);
    if (wv == 0) {
      for (int it = 0; it < 65536; ++it) {
        unsigned v = 0xFFFFFFFFu;
        if (lane < NWG)
          v = __hip_atomic_load(&flags[lane << 4], __ATOMIC_RELAXED,
                                __HIP_MEMORY_SCOPE_AGENT);
        if (__all(v >= target)) break;
        __builtin_amdgcn_s_sleep(1);
      }
    }
    __syncthreads();
    asm volatile("" ::: "memory");
  };
  barrier(1);   // h0 + all W slices staged everywhere

  // epilogue mapping (h-fragment store wave-coalesced):
  //   em = (lane&31) + 32*(wv&1);  c0 = (wv>>1)*16 + (lane>>5)*8;  k = n0g+c0
  //   -> fragment slot: mi_t = wv&1, kb = (n0g>>4)+(wv>>1), L = lane  (1 KB/wave)
  const int em  = (lane & 31) + 32 * (wv & 1);
  const int c0  = (wv >> 1) * 16 + (lane >> 5) * 8;
  const int kcol = n0g + c0;
  const int slot = ((wv & 1) * 64 + (n0g >> 4) + (wv >> 1)) * 64 + lane;
  float bias[8];
#pragma unroll
  for (int j = 0; j < 8; ++j) bias[j] = b_h[kcol + j];

  // prefetch step-0 token + embedding row
  int tok_n = x[em * Sz];
  float4 xv0_n = *(const float4*)&W_xh[(size_t)tok_n * Hz + kcol];
  float4 xv1_n = *(const float4*)&W_xh[(size_t)tok_n * Hz + kcol + 4];

  for (int s = 0; s < Sz; ++s) {
    const int p = s & 1;

    // coalesced coherent loads of all 16 A-fragments
    u32x4 t[16];
    load_afrags16(&g_hfrag[p][mi][ki * 16][lane][0], t);
    short8 a[16];
#pragma unroll
    for (int kst = 0; kst < 16; ++kst) a[kst] = *(short8*)&t[kst];

    f32x16 acc0 = {};  // cols [0,32) of slice  (B from registers)
    f32x16 acc1 = {};  // cols [32,64)          (B from LDS)
#pragma unroll
    for (int kst = 0; kst < 16; ++kst) {
      int kb8 = ki * 32 + kst * 2 + (lane >> 5);
      short8 b1 = *(const short8*)&ldsW1[(size_t)(kb8 * 32 + bn) * 8];
      acc0 = __builtin_amdgcn_mfma_f32_32x32x16_bf16(a[kst], b0r[kst], acc0, 0, 0, 0);
      acc1 = __builtin_amdgcn_mfma_f32_32x32x16_bf16(a[kst], b1,       acc1, 0, 0, 0);
    }

    // prefetch NEXT step's token + embedding row (hides gather latency)
    float4 xv0 = xv0_n, xv1 = xv1_n;
    if (s + 1 < Sz) {
      int t2 = x[em * Sz + s + 1];
      xv0_n = *(const float4*)&W_xh[(size_t)t2 * Hz + kcol];
      xv1_n = *(const float4*)&W_xh[(size_t)t2 * Hz + kcol + 4];
    }

    // single-sync 4-region K-split reduction (XOR-swizzled, conflict-free)
    // C/D: col=lane&31, row=(reg&3)+8*(reg>>2)+4*(lane>>5)  [m74/m101]
    {
      const int crow = 4 * (lane >> 5);
      float* reg = &red[ki * 4096];
#pragma unroll
      for (int r = 0; r < 16; ++r) {
        int m = mi * 32 + crow + (r & 3) + 8 * (r >> 2);
        reg[m * 64 + ((bn)      ^ (m & 31))] = acc0[r];
        reg[m * 64 + ((32 + bn) ^ (m & 31))] = acc1[r];
      }
    }
    __syncthreads();

    // epilogue: z = sum of 4 partials + emb + bias; h = tanh(z)
    float z[8];
    {
      const int sw = em & 31;
      const int base = em * 64;
#pragma unroll
      for (int j = 0; j < 8; ++j) {
        int off = base + ((c0 + j) ^ sw);
        z[j] = (red[off] + red[4096 + off]) + (red[8192 + off] + red[12288 + off]);
      }
    }
    z[0] = fast_tanh(z[0] + xv0.x + bias[0]);
    z[1] = fast_tanh(z[1] + xv0.y + bias[1]);
    z[2] = fast_tanh(z[2] + xv0.z + bias[2]);
    z[3] = fast_tanh(z[3] + xv0.w + bias[3]);
    z[4] = fast_tanh(z[4] + xv1.x + bias[4]);
    z[5] = fast_tanh(z[5] + xv1.y + bias[5]);
    z[6] = fast_tanh(z[6] + xv1.z + bias[6]);
    z[7] = fast_tanh(z[7] + xv1.w + bias[7]);

    u32x4 w;
    w.x = (unsigned)f2bf(z[0]) | ((unsigned)f2bf(z[1]) << 16);
    w.y = (unsigned)f2bf(z[2]) | ((unsigned)f2bf(z[3]) << 16);
    w.z = (unsigned)f2bf(z[4]) | ((unsigned)f2bf(z[5]) << 16);
    w.w = (unsigned)f2bf(z[6]) | ((unsigned)f2bf(z[7]) << 16);

    // h store: fragment layout, wave-coalesced (1 KB/wave), write-through
    store_frag_sc1(&((unsigned short*)g_hfrag)[((size_t)(p ^ 1) * 8192 + slot) * 8], w);

    if (s == Sz - 1) {
      *(u32x4*)&g_hidden[((size_t)s * 8192 + slot) * 8] = w;
      float* hf = out + (size_t)Bz * Sz * Vz + (size_t)em * Hz + kcol;
      float4 f0 = {z[0], z[1], z[2], z[3]};
      float4 f1 = {z[4], z[5], z[6], z[7]};
      *(float4*)&hf[0] = f0;
      *(float4*)&hf[4] = f1;
    } else {
      // split barrier: arrive (drain h stores + set flag), overlap the
      // g_hidden store with flag propagation, then wait.
      __syncthreads();                        // all waves' h-frag stores drained
      if (tid == 0)
        __hip_atomic_store(&flags[g << 4], (unsigned)(s + 2), __ATOMIC_RELAXED,
                           __HIP_MEMORY_SCOPE_AGENT);
      *(u32x4*)&g_hidden[((size_t)s * 8192 + slot) * 8] = w;   // overlapped
      if (wv == 0) {
        for (int it = 0; it < 65536; ++it) {
          unsigned v = 0xFFFFFFFFu;
          if (lane < NWG)
            v = __hip_atomic_load(&flags[lane << 4], __ATOMIC_RELAXED,
                                  __HIP_MEMORY_SCOPE_AGENT);
          if (__all(v >= (unsigned)(s + 2))) break;
          __builtin_amdgcn_s_sleep(1);
        }
      }
      __syncthreads();
      asm volatile("" ::: "memory");
    }
  }
}

// ---------------- Phase 2: logits = hidden @ W_out + b_out -------------------
// grid: 1024 blocks = (s, mi); 4 waves; wave nt computes 32 rows x 32 cols, K=1024
__global__ __launch_bounds__(256) void logits_gemm(
    const float* __restrict__ b_out, float* __restrict__ out)
{
  const int tid = threadIdx.x, lane = tid & 63, nt = tid >> 6;
  const int s = blockIdx.x >> 1, mi = blockIdx.x & 1;
  const unsigned short* ab = &g_hidden[((size_t)s * 8192 + (size_t)mi * 4096) * 8];

  f32x16 acc = {};
#pragma unroll 8
  for (int kb = 0; kb < 64; ++kb) {
    short8 a = *(const short8*)&ab[(size_t)(kb * 64 + lane) * 8];
    short8 b = *(const short8*)&g_wout[(size_t)((kb * 4 + nt) * 64 + lane) * 8];
    acc = __builtin_amdgcn_mfma_f32_32x32x16_bf16(a, b, acc, 0, 0, 0);
  }
  const int col = nt * 32 + (lane & 31);
  const float bo = b_out[col];
  const int rbase = 4 * (lane >> 5);
#pragma unroll
  for (int r = 0; r < 16; ++r) {
    int m = rbase + (r & 3) + 8 * (r >> 2);
    int em = mi * 32 + m;
    out[((size_t)em * Sz + s) * Vz + col] = acc[r] + bo;
  }
}

// ---------------- host launcher ----------------------------------------------
extern "C" void kernel_launch(void* const* d_in, const int* in_sizes, int n_in,
                              void* d_out, int out_size, void* d_ws, size_t ws_size,
                              hipStream_t stream) {
  const int*   x     = (const int*)d_in[0];
  const float* h0    = (const float*)d_in[1];
  const float* W_xh  = (const float*)d_in[2];
  const float* W_hh  = (const float*)d_in[3];
  const float* b_h   = (const float*)d_in[4];
  const float* W_out = (const float*)d_in[5];
  const float* b_out = (const float*)d_in[6];
  float* out = (float*)d_out;

  (void)hipMemsetAsync(d_ws, 0, 1024, stream);             // 16 wg-flag lines
  pack_wout<<<64, 256, 0, stream>>>(W_out);
  rnn_persistent<<<NWG, WGT, 0, stream>>>(x, h0, W_xh, W_hh, b_h, out,
                                          (unsigned*)d_ws);
  logits_gemm<<<Sz * 2, 256, 0, stream>>>(b_out, out);
}

// Round 12
// 2004.263 us; speedup vs baseline: 2.3288x; 1.0532x over previous
//
#include <hip/hip_runtime.h>
#include <hip/hip_bf16.h>
#include <stdint.h>

// SimpleRNN: B=64, S=512, H=1024, V=128
// Phase 1: persistent 16-wg recurrence (R8-proven arrival: syncthreads drain +
//   per-wg flag in d_ws). NEW: per-WAVE fine-grained WAIT on its 4 producer
//   wgs only (wave ki consumes kb in [16ki,16ki+16) <- wgs 4ki..4ki+3), with
//   TRIPLE-buffered h exchange (absorbs the 1-step skew the partial order
//   allows; proof in session notes). W_hh half in registers, half in LDS;
//   single-sync 4-region reduction; all spins bounded.
// Phase 2: logits GEMM (hidden bf16 @ W_out bf16, 32x32x16 MFMA) + b_out

#define Bz 64
#define Sz 512
#define Hz 1024
#define Vz 128
#define NWG 16
#define COLS 64   // Hz / NWG columns of W_hh per workgroup
#define WGT 512   // threads per wg (8 waves): 2 M-tiles x 4 K-splits

typedef __attribute__((ext_vector_type(8)))  short short8;
typedef __attribute__((ext_vector_type(16))) float f32x16;
typedef __attribute__((ext_vector_type(4)))  unsigned u32x4;   // asm-friendly 16B

// h TRIPLE buffer in MFMA A-fragment order:
// g_hfrag[gen][mi=m>>5][kb=k>>4][lane=((k>>3)&1)*32+(m&31)][j=k&7]
__device__ __align__(16) unsigned short g_hfrag[3][2][64][64][8];   // 3 x 128 KB
// hidden states, fragment order per step: [s][mi][kb][lane][8]  (64 MB)
__device__ __align__(16) unsigned short g_hidden[(size_t)Sz*2*64*64*8];
// W_out packed for 32x32x16 B-frags: [kb][nt][lane][8]  (256 KB)
__device__ __align__(16) unsigned short g_wout[64*4*64*8];

__device__ __forceinline__ unsigned short f2bf(float f) {
  union { float f; unsigned u; } v; v.f = f;
  unsigned r = v.u + 0x7FFFu + ((v.u >> 16) & 1u);      // RNE
  return (unsigned short)(r >> 16);
}

__device__ __forceinline__ float fast_tanh(float x) {
  float cx = fminf(9.0f, fmaxf(-9.0f, x));
  float e  = __builtin_amdgcn_exp2f(cx * 2.88539008178f);   // e^(2x)
  return (e - 1.0f) * __builtin_amdgcn_rcpf(e + 1.0f);
}

// 16 coherent (sc1 -> L3) 16-B loads; each instruction is a fully-coalesced
// 1 KB wave read (lane stride 16 B). Internal vmcnt(0) drain.  [R8-proven]
__device__ __forceinline__ void load_afrags16(const unsigned short* p0, u32x4 t[16]) {
  const unsigned short* p1 = p0 + 2048;   // +4096 B
  const unsigned short* p2 = p0 + 4096;   // +8192 B
  const unsigned short* p3 = p0 + 6144;   // +12288 B
  asm volatile(
    "global_load_dwordx4 %0,  %16, off sc1\n\t"
    "global_load_dwordx4 %1,  %16, off offset:1024 sc1\n\t"
    "global_load_dwordx4 %2,  %16, off offset:2048 sc1\n\t"
    "global_load_dwordx4 %3,  %16, off offset:3072 sc1\n\t"
    "global_load_dwordx4 %4,  %17, off sc1\n\t"
    "global_load_dwordx4 %5,  %17, off offset:1024 sc1\n\t"
    "global_load_dwordx4 %6,  %17, off offset:2048 sc1\n\t"
    "global_load_dwordx4 %7,  %17, off offset:3072 sc1\n\t"
    "global_load_dwordx4 %8,  %18, off sc1\n\t"
    "global_load_dwordx4 %9,  %18, off offset:1024 sc1\n\t"
    "global_load_dwordx4 %10, %18, off offset:2048 sc1\n\t"
    "global_load_dwordx4 %11, %18, off offset:3072 sc1\n\t"
    "global_load_dwordx4 %12, %19, off sc1\n\t"
    "global_load_dwordx4 %13, %19, off offset:1024 sc1\n\t"
    "global_load_dwordx4 %14, %19, off offset:2048 sc1\n\t"
    "global_load_dwordx4 %15, %19, off offset:3072 sc1\n\t"
    "s_waitcnt vmcnt(0)"
    : "=&v"(t[0]), "=&v"(t[1]), "=&v"(t[2]),  "=&v"(t[3]),
      "=&v"(t[4]), "=&v"(t[5]), "=&v"(t[6]),  "=&v"(t[7]),
      "=&v"(t[8]), "=&v"(t[9]), "=&v"(t[10]), "=&v"(t[11]),
      "=&v"(t[12]),"=&v"(t[13]),"=&v"(t[14]), "=&v"(t[15])
    : "v"(p0), "v"(p1), "v"(p2), "v"(p3)
    : "memory");
}

// agent-scope write-through 16-B store (visible at L3 once vmcnt retires)
__device__ __forceinline__ void store_frag_sc1(unsigned short* p, u32x4 v) {
  asm volatile("global_store_dwordx4 %0, %1, off sc1" :: "v"(p), "v"(v) : "memory");
}

// ---- Phase 0: pack W_out (H,V) fp32 -> [kb][nt][lane][8] bf16 (32x32 B-frag) --
__global__ void pack_wout(const float* __restrict__ W_out) {
  int gid = blockIdx.x * blockDim.x + threadIdx.x;      // 0..16383
  int lane = gid & 63;
  int nt   = (gid >> 6) & 3;
  int kb   = gid >> 8;
  int n = nt * 32 + (lane & 31);
  int k0 = kb * 16 + (lane >> 5) * 8;
  unsigned short t[8];
#pragma unroll
  for (int j = 0; j < 8; ++j)
    t[j] = f2bf(W_out[(size_t)(k0 + j) * Vz + n]);
  uint4 w;
  w.x = (unsigned)t[0] | ((unsigned)t[1] << 16);
  w.y = (unsigned)t[2] | ((unsigned)t[3] << 16);
  w.z = (unsigned)t[4] | ((unsigned)t[5] << 16);
  w.w = (unsigned)t[6] | ((unsigned)t[7] << 16);
  *(uint4*)&g_wout[(size_t)gid * 8] = w;
}

// ---------------- Phase 1: persistent recurrence -----------------------------
__global__ __launch_bounds__(WGT) void rnn_persistent(
    const int* __restrict__ x, const float* __restrict__ h0,
    const float* __restrict__ W_xh, const float* __restrict__ W_hh,
    const float* __restrict__ b_h, float* __restrict__ out,
    unsigned* __restrict__ flags)
{
  // W slice cols [32,64): fragment layout [kb8][n32][j] -> ds_read_b128
  __shared__ unsigned short ldsW1[128 * 32 * 8];        // 64 KB
  // 4 K-split partial regions, XOR-swizzled: red[ki*4096 + m*64 + (c^(m&31))]
  __shared__ float red[4 * 64 * 64];                    // 64 KB

  const int g    = blockIdx.x;        // 0..15
  const int n0g  = g * COLS;          // global column base of this wg's W slice
  const int tid  = threadIdx.x;
  const int lane = tid & 63;
  const int wv   = tid >> 6;          // 0..7
  const int mi   = wv & 1;            // M-tile (32 rows)
  const int ki   = wv >> 1;           // K-split (256 each)
  const int bn   = lane & 31;

  // ---- stage W_hh[:, n0g+32 : n0g+64) -> ldsW1 (one-time) ----
  for (int idx = tid; idx < 128 * 32; idx += WGT) {
    int kb = idx >> 5, n = idx & 31;
    unsigned short t[8];
#pragma unroll
    for (int j = 0; j < 8; ++j)
      t[j] = f2bf(W_hh[(size_t)(kb * 8 + j) * Hz + n0g + 32 + n]);
    uint4 w;
    w.x = (unsigned)t[0] | ((unsigned)t[1] << 16);
    w.y = (unsigned)t[2] | ((unsigned)t[3] << 16);
    w.z = (unsigned)t[4] | ((unsigned)t[5] << 16);
    w.w = (unsigned)t[6] | ((unsigned)t[7] << 16);
    *(uint4*)&ldsW1[(size_t)idx * 8] = w;
  }

  // ---- stage W_hh[:, n0g : n0g+32) -> REGISTERS (one-time, per wave ki) ----
  short8 b0r[16];
#pragma unroll
  for (int kst = 0; kst < 16; ++kst) {
    const float* wrow = &W_hh[(size_t)((ki * 32 + kst * 2 + (lane >> 5)) * 8) * Hz
                              + n0g + bn];
#pragma unroll
    for (int j = 0; j < 8; ++j)
      b0r[kst][j] = (short)f2bf(wrow[(size_t)j * Hz]);
  }

  // ---- h0 -> g_hfrag[0] (fragment order); wg g stages slots [g*512, g*512+512) ----
  {
    int s_idx = g * 512 + tid;              // 0..8191 over all wgs
    int fmi = s_idx >> 12, fkb = (s_idx >> 6) & 63, fL = s_idx & 63;
    int m = fmi * 32 + (fL & 31);
    int k = fkb * 16 + (fL >> 5) * 8;
    const float* src = &h0[(size_t)m * Hz + k];
    float4 a0 = *(const float4*)&src[0];
    float4 a1 = *(const float4*)&src[4];
    u32x4 w;
    w.x = (unsigned)f2bf(a0.x) | ((unsigned)f2bf(a0.y) << 16);
    w.y = (unsigned)f2bf(a0.z) | ((unsigned)f2bf(a0.w) << 16);
    w.z = (unsigned)f2bf(a1.x) | ((unsigned)f2bf(a1.y) << 16);
    w.w = (unsigned)f2bf(a1.z) | ((unsigned)f2bf(a1.w) << 16);
    store_frag_sc1(&g_hfrag[0][fmi][fkb][fL][0], w);
  }

  // ---- initial FULL barrier (R8 form): h0 + W staged everywhere ----
  {
    __syncthreads();
    if (tid == 0)
      __hip_atomic_store(&flags[g << 4], 1u, __ATOMIC_RELAXED,
                         __HIP_MEMORY_SCOPE_AGENT);
    if (wv == 0) {
      for (int it = 0; it < 65536; ++it) {
        unsigned v = 0xFFFFFFFFu;
        if (lane < NWG)
          v = __hip_atomic_load(&flags[lane << 4], __ATOMIC_RELAXED,
                                __HIP_MEMORY_SCOPE_AGENT);
        if (__all(v >= 1u)) break;
        __builtin_amdgcn_s_sleep(1);
      }
    }
    __syncthreads();
    asm volatile("" ::: "memory");
  }

  // epilogue mapping (h-fragment store wave-coalesced):
  //   em = (lane&31) + 32*(wv&1);  c0 = (wv>>1)*16 + (lane>>5)*8;  k = n0g+c0
  //   -> fragment slot: mi_t = wv&1, kb = (n0g>>4)+(wv>>1), L = lane  (1 KB/wave)
  const int em  = (lane & 31) + 32 * (wv & 1);
  const int c0  = (wv >> 1) * 16 + (lane >> 5) * 8;
  const int kcol = n0g + c0;
  const int slot = ((wv & 1) * 64 + (n0g >> 4) + (wv >> 1)) * 64 + lane;
  float bias[8];
#pragma unroll
  for (int j = 0; j < 8; ++j) bias[j] = b_h[kcol + j];

  // this wave's 4 producer wgs: flags[4ki + 0..3] (lane j<4 watches producer j)
  const int pflag = (4 * ki + (lane & 3)) << 4;

  // prefetch step-0 token + embedding row
  int tok_n = x[em * Sz];
  float4 xv0_n = *(const float4*)&W_xh[(size_t)tok_n * Hz + kcol];
  float4 xv1_n = *(const float4*)&W_xh[(size_t)tok_n * Hz + kcol + 4];

  int rp = 0;                               // read generation = s % 3
  for (int s = 0; s < Sz; ++s) {
    const int wp = (rp == 2) ? 0 : rp + 1;  // write generation

    // coalesced coherent loads of all 16 A-fragments
    u32x4 t[16];
    load_afrags16(&g_hfrag[rp][mi][ki * 16][lane][0], t);
    short8 a[16];
#pragma unroll
    for (int kst = 0; kst < 16; ++kst) a[kst] = *(short8*)&t[kst];

    f32x16 acc0 = {};  // cols [0,32) of slice  (B from registers)
    f32x16 acc1 = {};  // cols [32,64)          (B from LDS)
#pragma unroll
    for (int kst = 0; kst < 16; ++kst) {
      int kb8 = ki * 32 + kst * 2 + (lane >> 5);
      short8 b1 = *(const short8*)&ldsW1[(size_t)(kb8 * 32 + bn) * 8];
      acc0 = __builtin_amdgcn_mfma_f32_32x32x16_bf16(a[kst], b0r[kst], acc0, 0, 0, 0);
      acc1 = __builtin_amdgcn_mfma_f32_32x32x16_bf16(a[kst], b1,       acc1, 0, 0, 0);
    }

    // prefetch NEXT step's token + embedding row (hides gather latency)
    float4 xv0 = xv0_n, xv1 = xv1_n;
    if (s + 1 < Sz) {
      int t2 = x[em * Sz + s + 1];
      xv0_n = *(const float4*)&W_xh[(size_t)t2 * Hz + kcol];
      xv1_n = *(const float4*)&W_xh[(size_t)t2 * Hz + kcol + 4];
    }

    // single-sync 4-region K-split reduction (XOR-swizzled, conflict-free)
    // C/D: col=lane&31, row=(reg&3)+8*(reg>>2)+4*(lane>>5)  [m74/m101]
    {
      const int crow = 4 * (lane >> 5);
      float* reg = &red[ki * 4096];
#pragma unroll
      for (int r = 0; r < 16; ++r) {
        int m = mi * 32 + crow + (r & 3) + 8 * (r >> 2);
        reg[m * 64 + ((bn)      ^ (m & 31))] = acc0[r];
        reg[m * 64 + ((32 + bn) ^ (m & 31))] = acc1[r];
      }
    }
    __syncthreads();

    // epilogue: z = sum of 4 partials + emb + bias; h = tanh(z)
    float z[8];
    {
      const int sw = em & 31;
      const int base = em * 64;
#pragma unroll
      for (int j = 0; j < 8; ++j) {
        int off = base + ((c0 + j) ^ sw);
        z[j] = (red[off] + red[4096 + off]) + (red[8192 + off] + red[12288 + off]);
      }
    }
    z[0] = fast_tanh(z[0] + xv0.x + bias[0]);
    z[1] = fast_tanh(z[1] + xv0.y + bias[1]);
    z[2] = fast_tanh(z[2] + xv0.z + bias[2]);
    z[3] = fast_tanh(z[3] + xv0.w + bias[3]);
    z[4] = fast_tanh(z[4] + xv1.x + bias[4]);
    z[5] = fast_tanh(z[5] + xv1.y + bias[5]);
    z[6] = fast_tanh(z[6] + xv1.z + bias[6]);
    z[7] = fast_tanh(z[7] + xv1.w + bias[7]);

    u32x4 w;
    w.x = (unsigned)f2bf(z[0]) | ((unsigned)f2bf(z[1]) << 16);
    w.y = (unsigned)f2bf(z[2]) | ((unsigned)f2bf(z[3]) << 16);
    w.z = (unsigned)f2bf(z[4]) | ((unsigned)f2bf(z[5]) << 16);
    w.w = (unsigned)f2bf(z[6]) | ((unsigned)f2bf(z[7]) << 16);

    // h store: fragment layout, wave-coalesced (1 KB/wave), write-through
    store_frag_sc1(&((unsigned short*)g_hfrag)[((size_t)wp * 8192 + slot) * 8], w);

    if (s == Sz - 1) {
      *(u32x4*)&g_hidden[((size_t)s * 8192 + slot) * 8] = w;
      float* hf = out + (size_t)Bz * Sz * Vz + (size_t)em * Hz + kcol;
      float4 f0 = {z[0], z[1], z[2], z[3]};
      float4 f1 = {z[4], z[5], z[6], z[7]};
      *(float4*)&hf[0] = f0;
      *(float4*)&hf[4] = f1;
    } else {
      // arrival (R8-proven): syncthreads drains all waves' h stores, then
      // tid0 publishes the wg flag.
      __syncthreads();
      if (tid == 0)
        __hip_atomic_store(&flags[g << 4], (unsigned)(s + 2), __ATOMIC_RELAXED,
                           __HIP_MEMORY_SCOPE_AGENT);
      // overlapped with flag propagation:
      *(u32x4*)&g_hidden[((size_t)s * 8192 + slot) * 8] = w;
      // fine-grained WAIT: only this wave's 4 producer wgs (bounded spin)
      {
        const unsigned tgt = (unsigned)(s + 2);
        for (int it = 0; it < 65536; ++it) {
          unsigned v = 0xFFFFFFFFu;
          if (lane < 4)
            v = __hip_atomic_load(&flags[pflag], __ATOMIC_RELAXED,
                                  __HIP_MEMORY_SCOPE_AGENT);
          if (__all(v >= tgt)) break;
          __builtin_amdgcn_s_sleep(1);
        }
      }
      asm volatile("" ::: "memory");
    }
    rp = wp;
  }
}

// ---------------- Phase 2: logits = hidden @ W_out + b_out -------------------
// grid: 1024 blocks = (s, mi); 4 waves; wave nt computes 32 rows x 32 cols, K=1024
__global__ __launch_bounds__(256) void logits_gemm(
    const float* __restrict__ b_out, float* __restrict__ out)
{
  const int tid = threadIdx.x, lane = tid & 63, nt = tid >> 6;
  const int s = blockIdx.x >> 1, mi = blockIdx.x & 1;
  const unsigned short* ab = &g_hidden[((size_t)s * 8192 + (size_t)mi * 4096) * 8];

  f32x16 acc = {};
#pragma unroll 8
  for (int kb = 0; kb < 64; ++kb) {
    short8 a = *(const short8*)&ab[(size_t)(kb * 64 + lane) * 8];
    short8 b = *(const short8*)&g_wout[(size_t)((kb * 4 + nt) * 64 + lane) * 8];
    acc = __builtin_amdgcn_mfma_f32_32x32x16_bf16(a, b, acc, 0, 0, 0);
  }
  const int col = nt * 32 + (lane & 31);
  const float bo = b_out[col];
  const int rbase = 4 * (lane >> 5);
#pragma unroll
  for (int r = 0; r < 16; ++r) {
    int m = rbase + (r & 3) + 8 * (r >> 2);
    int em = mi * 32 + m;
    out[((size_t)em * Sz + s) * Vz + col] = acc[r] + bo;
  }
}

// ---------------- host launcher ----------------------------------------------
extern "C" void kernel_launch(void* const* d_in, const int* in_sizes, int n_in,
                              void* d_out, int out_size, void* d_ws, size_t ws_size,
                              hipStream_t stream) {
  const int*   x     = (const int*)d_in[0];
  const float* h0    = (const float*)d_in[1];
  const float* W_xh  = (const float*)d_in[2];
  const float* W_hh  = (const float*)d_in[3];
  const float* b_h   = (const float*)d_in[4];
  const float* W_out = (const float*)d_in[5];
  const float* b_out = (const float*)d_in[6];
  float* out = (float*)d_out;

  (void)hipMemsetAsync(d_ws, 0, 1024, stream);             // 16 wg-flag lines
  pack_wout<<<64, 256, 0, stream>>>(W_out);
  rnn_persistent<<<NWG, WGT, 0, stream>>>(x, h0, W_xh, W_hh, b_h, out,
                                          (unsigned*)d_ws);
  logits_gemm<<<Sz * 2, 256, 0, stream>>>(b_out, out);
}

// Round 13
// 1724.289 us; speedup vs baseline: 2.7069x; 1.1624x over previous
//
#include <hip/hip_runtime.h>
#include <hip/hip_bf16.h>
#include <stdint.h>

// SimpleRNN: B=64, S=512, H=1024, V=128
// Phase 1: persistent 32-wg recurrence, 32 cols of W_hh per wg (LDS, 64 KB).
//   R8-proven protocol: wg-level flags in d_ws (32 x 32 B = 1024 B), arrival =
//   syncthreads drain + tid0 flag store; per-wave fine wait on its 8 producer
//   wgs; TRIPLE-buffered h exchange in MFMA A-fragment layout via sc1/L3.
//   96 KB LDS forces max 1 wg/CU -> dispatcher must spread all 32 wgs.
// Phase 2: logits GEMM (hidden bf16 @ W_out bf16, 32x32x16 MFMA) + b_out

#define Bz 64
#define Sz 512
#define Hz 1024
#define Vz 128
#define NWG 32
#define COLS 32   // Hz / NWG columns of W_hh per workgroup
#define WGT 512   // threads per wg (8 waves): 2 M-tiles x 4 K-splits

typedef __attribute__((ext_vector_type(8)))  short short8;
typedef __attribute__((ext_vector_type(16))) float f32x16;
typedef __attribute__((ext_vector_type(4)))  unsigned u32x4;   // asm-friendly 16B
typedef __attribute__((ext_vector_type(2)))  unsigned u32x2;   // asm-friendly 8B

// h TRIPLE buffer in MFMA A-fragment order:
// g_hfrag[gen][mi=m>>5][kb=k>>4][lane=((k>>3)&1)*32+(m&31)][j=k&7]
__device__ __align__(16) unsigned short g_hfrag[3][2][64][64][8];   // 3 x 128 KB
// hidden states, fragment order per step: [s][mi][kb][lane][8]  (64 MB)
__device__ __align__(16) unsigned short g_hidden[(size_t)Sz*2*64*64*8];
// W_out packed for 32x32x16 B-frags: [kb][nt][lane][8]  (256 KB)
__device__ __align__(16) unsigned short g_wout[64*4*64*8];

__device__ __forceinline__ unsigned short f2bf(float f) {
  union { float f; unsigned u; } v; v.f = f;
  unsigned r = v.u + 0x7FFFu + ((v.u >> 16) & 1u);      // RNE
  return (unsigned short)(r >> 16);
}

__device__ __forceinline__ float fast_tanh(float x) {
  float cx = fminf(9.0f, fmaxf(-9.0f, x));
  float e  = __builtin_amdgcn_exp2f(cx * 2.88539008178f);   // e^(2x)
  return (e - 1.0f) * __builtin_amdgcn_rcpf(e + 1.0f);
}

// 16 coherent (sc1 -> L3) 16-B loads; each instruction is a fully-coalesced
// 1 KB wave read (lane stride 16 B). Internal vmcnt(0) drain.  [R8-proven]
__device__ __forceinline__ void load_afrags16(const unsigned short* p0, u32x4 t[16]) {
  const unsigned short* p1 = p0 + 2048;   // +4096 B
  const unsigned short* p2 = p0 + 4096;   // +8192 B
  const unsigned short* p3 = p0 + 6144;   // +12288 B
  asm volatile(
    "global_load_dwordx4 %0,  %16, off sc1\n\t"
    "global_load_dwordx4 %1,  %16, off offset:1024 sc1\n\t"
    "global_load_dwordx4 %2,  %16, off offset:2048 sc1\n\t"
    "global_load_dwordx4 %3,  %16, off offset:3072 sc1\n\t"
    "global_load_dwordx4 %4,  %17, off sc1\n\t"
    "global_load_dwordx4 %5,  %17, off offset:1024 sc1\n\t"
    "global_load_dwordx4 %6,  %17, off offset:2048 sc1\n\t"
    "global_load_dwordx4 %7,  %17, off offset:3072 sc1\n\t"
    "global_load_dwordx4 %8,  %18, off sc1\n\t"
    "global_load_dwordx4 %9,  %18, off offset:1024 sc1\n\t"
    "global_load_dwordx4 %10, %18, off offset:2048 sc1\n\t"
    "global_load_dwordx4 %11, %18, off offset:3072 sc1\n\t"
    "global_load_dwordx4 %12, %19, off sc1\n\t"
    "global_load_dwordx4 %13, %19, off offset:1024 sc1\n\t"
    "global_load_dwordx4 %14, %19, off offset:2048 sc1\n\t"
    "global_load_dwordx4 %15, %19, off offset:3072 sc1\n\t"
    "s_waitcnt vmcnt(0)"
    : "=&v"(t[0]), "=&v"(t[1]), "=&v"(t[2]),  "=&v"(t[3]),
      "=&v"(t[4]), "=&v"(t[5]), "=&v"(t[6]),  "=&v"(t[7]),
      "=&v"(t[8]), "=&v"(t[9]), "=&v"(t[10]), "=&v"(t[11]),
      "=&v"(t[12]),"=&v"(t[13]),"=&v"(t[14]), "=&v"(t[15])
    : "v"(p0), "v"(p1), "v"(p2), "v"(p3)
    : "memory");
}

// agent-scope write-through stores (visible at L3 once vmcnt retires)
__device__ __forceinline__ void store16_sc1(unsigned short* p, u32x4 v) {
  asm volatile("global_store_dwordx4 %0, %1, off sc1" :: "v"(p), "v"(v) : "memory");
}
__device__ __forceinline__ void store8_sc1(unsigned short* p, u32x2 v) {
  asm volatile("global_store_dwordx2 %0, %1, off sc1" :: "v"(p), "v"(v) : "memory");
}

// ---- Phase 0: pack W_out (H,V) fp32 -> [kb][nt][lane][8] bf16 (32x32 B-frag) --
__global__ void pack_wout(const float* __restrict__ W_out) {
  int gid = blockIdx.x * blockDim.x + threadIdx.x;      // 0..16383
  int lane = gid & 63;
  int nt   = (gid >> 6) & 3;
  int kb   = gid >> 8;
  int n = nt * 32 + (lane & 31);
  int k0 = kb * 16 + (lane >> 5) * 8;
  unsigned short t[8];
#pragma unroll
  for (int j = 0; j < 8; ++j)
    t[j] = f2bf(W_out[(size_t)(k0 + j) * Vz + n]);
  uint4 w;
  w.x = (unsigned)t[0] | ((unsigned)t[1] << 16);
  w.y = (unsigned)t[2] | ((unsigned)t[3] << 16);
  w.z = (unsigned)t[4] | ((unsigned)t[5] << 16);
  w.w = (unsigned)t[6] | ((unsigned)t[7] << 16);
  *(uint4*)&g_wout[(size_t)gid * 8] = w;
}

// ---------------- Phase 1: persistent recurrence -----------------------------
__global__ __launch_bounds__(WGT) void rnn_persistent(
    const int* __restrict__ x, const float* __restrict__ h0,
    const float* __restrict__ W_xh, const float* __restrict__ W_hh,
    const float* __restrict__ b_h, float* __restrict__ out,
    unsigned* __restrict__ flags)
{
  // W slice (32 cols): fragment layout [kb8][n32][j] -> ds_read_b128
  __shared__ unsigned short ldsW[128 * 32 * 8];         // 64 KB
  // 4 K-split partial regions, XOR-swizzled: red[ki*2048 + m*32 + (c^(m&31))]
  __shared__ float red[4 * 64 * 32];                    // 32 KB
  // 96 KB total -> at most 1 wg per CU (forces spreading of all 32 wgs)

  const int g    = blockIdx.x;        // 0..31
  const int n0g  = g * COLS;          // global column base of this wg's W slice
  const int tid  = threadIdx.x;
  const int lane = tid & 63;
  const int wv   = tid >> 6;          // 0..7
  const int mi   = wv & 1;            // M-tile (32 rows)
  const int ki   = wv >> 1;           // K-split (256 each)
  const int bn   = lane & 31;

  // ---- stage W_hh[:, n0g : n0g+32) -> ldsW (one-time) ----
  for (int idx = tid; idx < 128 * 32; idx += WGT) {
    int kb = idx >> 5, n = idx & 31;
    unsigned short t[8];
#pragma unroll
    for (int j = 0; j < 8; ++j)
      t[j] = f2bf(W_hh[(size_t)(kb * 8 + j) * Hz + n0g + n]);
    uint4 w;
    w.x = (unsigned)t[0] | ((unsigned)t[1] << 16);
    w.y = (unsigned)t[2] | ((unsigned)t[3] << 16);
    w.z = (unsigned)t[4] | ((unsigned)t[5] << 16);
    w.w = (unsigned)t[6] | ((unsigned)t[7] << 16);
    *(uint4*)&ldsW[(size_t)idx * 8] = w;
  }

  // ---- h0 -> g_hfrag[0]; wg g stages slots [g*256, g*256+256) ----
  if (tid < 256) {
    int s_idx = g * 256 + tid;              // 0..8191 over all wgs
    int fmi = s_idx >> 12, fkb = (s_idx >> 6) & 63, fL = s_idx & 63;
    int m = fmi * 32 + (fL & 31);
    int k = fkb * 16 + (fL >> 5) * 8;
    const float* src = &h0[(size_t)m * Hz + k];
    float4 a0 = *(const float4*)&src[0];
    float4 a1 = *(const float4*)&src[4];
    u32x4 w;
    w.x = (unsigned)f2bf(a0.x) | ((unsigned)f2bf(a0.y) << 16);
    w.y = (unsigned)f2bf(a0.z) | ((unsigned)f2bf(a0.w) << 16);
    w.z = (unsigned)f2bf(a1.x) | ((unsigned)f2bf(a1.y) << 16);
    w.w = (unsigned)f2bf(a1.z) | ((unsigned)f2bf(a1.w) << 16);
    store16_sc1(&g_hfrag[0][fmi][fkb][fL][0], w);
  }

  // ---- initial FULL barrier (R8 form): h0 + W staged everywhere ----
  {
    __syncthreads();
    if (tid == 0)
      __hip_atomic_store(&flags[g * 8], 1u, __ATOMIC_RELAXED,
                         __HIP_MEMORY_SCOPE_AGENT);
    if (wv == 0) {
      for (int it = 0; it < 65536; ++it) {
        unsigned v = 0xFFFFFFFFu;
        if (lane < NWG)
          v = __hip_atomic_load(&flags[lane * 8], __ATOMIC_RELAXED,
                                __HIP_MEMORY_SCOPE_AGENT);
        if (__all(v >= 1u)) break;
        __builtin_amdgcn_s_sleep(1);
      }
    }
    __syncthreads();
    asm volatile("" ::: "memory");
  }

  // epilogue mapping: em = (lane&31)+32*(wv&1) (row), 4 cols at c0
  //   c0 = ((wv>>1)*2 + (lane>>5)) * 4  in [0,32)
  // h-frag slot (8-B store, wave-coalesced into full 128-B lines):
  const int em   = (lane & 31) + 32 * (wv & 1);
  const int c0   = ((wv >> 1) * 2 + (lane >> 5)) * 4;
  const int kcol = n0g + c0;
  const int kb_g = kcol >> 4;                 // global kb plane (2g or 2g+1)
  const int kq   = (c0 >> 3) & 1;
  const int lslot = kq * 32 + (em & 31);
  const size_t slotOff =
      ((((size_t)(wv & 1) * 64 + kb_g) * 64) + lslot) * 8 + (c0 & 7);
  float bias[4];
#pragma unroll
  for (int j = 0; j < 4; ++j) bias[j] = b_h[kcol + j];

  // this wave's 8 producer wgs: flags[(8ki+0..7)*8] (lane j<8 watches one)
  const int pflag = (8 * ki + (lane & 7)) * 8;

  // prefetch step-0 token + embedding row
  int tok_n = x[em * Sz];
  float4 xv_n = *(const float4*)&W_xh[(size_t)tok_n * Hz + kcol];

  int rp = 0;                               // read generation = s % 3
  for (int s = 0; s < Sz; ++s) {
    const int wp = (rp == 2) ? 0 : rp + 1;  // write generation

    // coalesced coherent loads of all 16 A-fragments
    u32x4 t[16];
    load_afrags16(&g_hfrag[rp][mi][ki * 16][lane][0], t);
    short8 a[16];
#pragma unroll
    for (int kst = 0; kst < 16; ++kst) a[kst] = *(short8*)&t[kst];

    f32x16 acc = {};   // this wg's 32 cols, K-quarter ki
#pragma unroll
    for (int kst = 0; kst < 16; ++kst) {
      int kb8 = ki * 32 + kst * 2 + (lane >> 5);
      short8 b = *(const short8*)&ldsW[(size_t)(kb8 * 32 + bn) * 8];
      acc = __builtin_amdgcn_mfma_f32_32x32x16_bf16(a[kst], b, acc, 0, 0, 0);
    }

    // prefetch NEXT step's token + embedding row (hides gather latency)
    float4 xv = xv_n;
    if (s + 1 < Sz) {
      int t2 = x[em * Sz + s + 1];
      xv_n = *(const float4*)&W_xh[(size_t)t2 * Hz + kcol];
    }

    // single-sync 4-region K-split reduction (XOR-swizzled, <=2-way banks)
    // C/D: col=lane&31, row=(reg&3)+8*(reg>>2)+4*(lane>>5)  [m74/m101]
    {
      const int crow = 4 * (lane >> 5);
      float* reg = &red[ki * 2048];
#pragma unroll
      for (int r = 0; r < 16; ++r) {
        int m = mi * 32 + crow + (r & 3) + 8 * (r >> 2);
        reg[m * 32 + (bn ^ (m & 31))] = acc[r];
      }
    }
    __syncthreads();

    // epilogue: z = sum of 4 partials + emb + bias; h = tanh(z)
    float z[4];
    {
      const int sw = em & 31;
      const int base = em * 32;
#pragma unroll
      for (int j = 0; j < 4; ++j) {
        int off = base + ((c0 + j) ^ sw);
        z[j] = (red[off] + red[2048 + off]) + (red[4096 + off] + red[6144 + off]);
      }
    }
    z[0] = fast_tanh(z[0] + xv.x + bias[0]);
    z[1] = fast_tanh(z[1] + xv.y + bias[1]);
    z[2] = fast_tanh(z[2] + xv.z + bias[2]);
    z[3] = fast_tanh(z[3] + xv.w + bias[3]);

    u32x2 w2;
    w2.x = (unsigned)f2bf(z[0]) | ((unsigned)f2bf(z[1]) << 16);
    w2.y = (unsigned)f2bf(z[2]) | ((unsigned)f2bf(z[3]) << 16);

    // h store: fragment layout, wave-coalesced, write-through to L3
    store8_sc1(&((unsigned short*)g_hfrag)[(size_t)wp * 65536 + slotOff], w2);

    if (s == Sz - 1) {
      *(u32x2*)&g_hidden[(size_t)s * 65536 + slotOff] = w2;
      float* hf = out + (size_t)Bz * Sz * Vz + (size_t)em * Hz + kcol;
      float4 f0 = {z[0], z[1], z[2], z[3]};
      *(float4*)hf = f0;
    } else {
      // arrival (R8-proven): syncthreads drains all waves' h stores, then
      // tid0 publishes the wg flag.
      __syncthreads();
      if (tid == 0)
        __hip_atomic_store(&flags[g * 8], (unsigned)(s + 2), __ATOMIC_RELAXED,
                           __HIP_MEMORY_SCOPE_AGENT);
      // overlapped with flag propagation:
      *(u32x2*)&g_hidden[(size_t)s * 65536 + slotOff] = w2;
      // fine-grained WAIT: only this wave's 8 producer wgs (bounded spin)
      {
        const unsigned tgt = (unsigned)(s + 2);
        for (int it = 0; it < 65536; ++it) {
          unsigned v = 0xFFFFFFFFu;
          if (lane < 8)
            v = __hip_atomic_load(&flags[pflag], __ATOMIC_RELAXED,
                                  __HIP_MEMORY_SCOPE_AGENT);
          if (__all(v >= tgt)) break;
          __builtin_amdgcn_s_sleep(1);
        }
      }
      asm volatile("" ::: "memory");
    }
    rp = wp;
  }
}

// ---------------- Phase 2: logits = hidden @ W_out + b_out -------------------
// grid: 1024 blocks = (s, mi); 4 waves; wave nt computes 32 rows x 32 cols, K=1024
__global__ __launch_bounds__(256) void logits_gemm(
    const float* __restrict__ b_out, float* __restrict__ out)
{
  const int tid = threadIdx.x, lane = tid & 63, nt = tid >> 6;
  const int s = blockIdx.x >> 1, mi = blockIdx.x & 1;
  const unsigned short* ab = &g_hidden[((size_t)s * 8192 + (size_t)mi * 4096) * 8];

  f32x16 acc = {};
#pragma unroll 8
  for (int kb = 0; kb < 64; ++kb) {
    short8 a = *(const short8*)&ab[(size_t)(kb * 64 + lane) * 8];
    short8 b = *(const short8*)&g_wout[(size_t)((kb * 4 + nt) * 64 + lane) * 8];
    acc = __builtin_amdgcn_mfma_f32_32x32x16_bf16(a, b, acc, 0, 0, 0);
  }
  const int col = nt * 32 + (lane & 31);
  const float bo = b_out[col];
  const int rbase = 4 * (lane >> 5);
#pragma unroll
  for (int r = 0; r < 16; ++r) {
    int m = rbase + (r & 3) + 8 * (r >> 2);
    int em = mi * 32 + m;
    out[((size_t)em * Sz + s) * Vz + col] = acc[r] + bo;
  }
}

// ---------------- host launcher ----------------------------------------------
extern "C" void kernel_launch(void* const* d_in, const int* in_sizes, int n_in,
                              void* d_out, int out_size, void* d_ws, size_t ws_size,
                              hipStream_t stream) {
  const int*   x     = (const int*)d_in[0];
  const float* h0    = (const float*)d_in[1];
  const float* W_xh  = (const float*)d_in[2];
  const float* W_hh  = (const float*)d_in[3];
  const float* b_h   = (const float*)d_in[4];
  const float* W_out = (const float*)d_in[5];
  const float* b_out = (const float*)d_in[6];
  float* out = (float*)d_out;

  (void)hipMemsetAsync(d_ws, 0, 1024, stream);    // 32 wg-flag lines (32 B each)
  pack_wout<<<64, 256, 0, stream>>>(W_out);
  rnn_persistent<<<NWG, WGT, 0, stream>>>(x, h0, W_xh, W_hh, b_h, out,
                                          (unsigned*)d_ws);
  logits_gemm<<<Sz * 2, 256, 0, stream>>>(b_out, out);
}